// Round 1
// baseline (1566.247 us; speedup 1.0000x reference)
//
#include <hip/hip_runtime.h>
#include <math.h>

#define HWC 1024      // H*W
#define NB  32        // batch
#define GH  32
#define GW  32

__device__ __forceinline__ void combineMax(float& bv, int& bi, float ov, int oi) {
    // first-index-wins argmax combine
    if (ov > bv || (ov == bv && oi < bi)) { bv = ov; bi = oi; }
}

// PHASE 1: record per-step solved bits (no parents). PHASE 2: full sim to ctrl[0], outputs.
template<int PHASE>
__global__ __launch_bounds__(256)
void dastar_sim(const float* __restrict__ cm_g, const float* __restrict__ sm_g,
                const float* __restrict__ gm_g, unsigned* __restrict__ sw,
                const int* __restrict__ ctrl, float* __restrict__ out)
{
    const int b   = blockIdx.x;
    const int tid = threadIdx.x;
    const int lane = tid & 63;

    __shared__ float cm[HWC], hh[HWC], gg[HWC], oo[HWC], hi[HWC];
    __shared__ float pp[(PHASE == 2) ? HWC : 4];
    __shared__ unsigned mask[32];
    __shared__ float wv[4];
    __shared__ int   wi[4];
    __shared__ int   goal_sh, stop_sh;

    // ---- load inputs (float4 vectorized; thread owns cells 4*tid..4*tid+3) ----
    float4 c4 = ((const float4*)(cm_g + b * HWC))[tid];
    float4 s4 = ((const float4*)(sm_g + b * HWC))[tid];
    float4 g4 = ((const float4*)(gm_g + b * HWC))[tid];
    float cv[4]  = {c4.x, c4.y, c4.z, c4.w};
    float svv[4] = {s4.x, s4.y, s4.z, s4.w};
    float gvv[4] = {g4.x, g4.y, g4.z, g4.w};
#pragma unroll
    for (int k = 0; k < 4; ++k) {
        int i = tid * 4 + k;
        cm[i] = cv[k];
        gg[i] = 0.0f;
        hi[i] = 0.0f;
        oo[i] = svv[k];                  // start one-hot
        if (gvv[k] == 1.0f) goal_sh = i; // unique goal cell
    }
    if (tid < 32) mask[tid] = 0u;
    if (tid == 0) stop_sh = 0;
    __syncthreads();

    const int   goal = goal_sh;
    const float gy = (float)(goal >> 5), gx = (float)(goal & 31);
#pragma unroll
    for (int k = 0; k < 4; ++k) {
        int i = tid * 4 + k;
        float dy = (float)(i >> 5) - gy;   // exact small ints
        float dx = (float)(i & 31) - gx;
        // dy*dy + dx*dx is exact (integers <= 1922); sqrtf correctly rounded; one rounding on *cm
        hh[i] = __fmul_rn(sqrtf(__fadd_rn(__fmul_rn(dy, dy), __fmul_rn(dx, dx))), cm[i]);
        if (PHASE == 2) pp[i] = (float)goal;   // parents0 = goal_idx
    }
    __syncthreads();

    const int Tend = (PHASE == 1) ? (HWC - 1) : ctrl[0];

    for (int t = 0; t <= Tend; ++t) {
        // ---- f_exp + local argmax over this thread's 4 cells (ascending index => first-max) ----
        float bv = -1.0f; int bi = 0;
#pragma unroll
        for (int k = 0; k < 4; ++k) {
            int i = tid * 4 + k;
            float f  = __fadd_rn(gg[i], hh[i]);
            // -f*inv_c with inv_c = 0.03125 is an exact scaling; expf then one rounding on *open
            float fe = __fmul_rn(expf(__fmul_rn(f, -0.03125f)), oo[i]);
            if (fe > bv) { bv = fe; bi = i; }
        }
        // ---- wave butterfly argmax (64 lanes) ----
#pragma unroll
        for (int m = 32; m >= 1; m >>= 1) {
            float ov = __shfl_xor(bv, m);
            int   oi = __shfl_xor(bi, m);
            combineMax(bv, bi, ov, oi);
        }
        if (lane == 0) { wv[tid >> 6] = bv; wi[tid >> 6] = bi; }
        __syncthreads();

        if (tid < 64) {
            float fv = wv[0]; int fi = wi[0];
            combineMax(fv, fi, wv[1], wi[1]);
            combineMax(fv, fi, wv[2], wi[2]);
            combineMax(fv, fi, wv[3], wi[3]);
            const int  s      = fi;
            const bool solved = (s == goal);
            bool blocking = false;

            if (tid < 8) {
                // 8-neighborhood update (conv3x3 with one-hot ns collapses to this)
                const int dy8[8] = {-1,-1,-1, 0, 0, 1, 1, 1};
                const int dx8[8] = {-1, 0, 1,-1, 1,-1, 0, 1};
                int sy = s >> 5, sx = s & 31;
                int cy = sy + dy8[tid], cx = sx + dx8[tid];
                if (cy >= 0 && cy < GH && cx >= 0 && cx < GW) {
                    int   c   = (cy << 5) | cx;
                    float kc  = (dy8[tid] != 0 && dx8[tid] != 0) ? 1.4142f : 1.0f;
                    float g2  = __fadd_rn(gg[s], kc);              // (g*ns).sum + conv(ns,k_c)
                    float oc  = oo[c], hc = hi[c], gc = gg[c], cmc = cm[c];
                    float t1  = __fmul_rn(__fsub_rn(1.0f, oc), __fsub_rn(1.0f, hc));
                    float t2  = __fmul_rn(oc, (gc > g2) ? 1.0f : 0.0f);
                    float idxv = __fmul_rn(__fadd_rn(t1, t2), cmc); // idx = (...) * neighbor(=cm)
                    if (idxv != 0.0f) {
                        blocking = true;
                        float omi = __fsub_rn(1.0f, idxv);
                        gg[c] = __fadd_rn(__fmul_rn(g2, idxv), __fmul_rn(gc, omi));
                        oo[c] = fminf(__fadd_rn(oc, idxv), 1.0f);  // clip upper; lower bound can't trigger
                        if (PHASE == 2)
                            pp[c] = __fadd_rn(__fmul_rn((float)s, idxv), __fmul_rn(pp[c], omi));
                    }
                }
            } else if (tid == 8) {
                // selected-cell updates: hist |= ns ; open -= unsolved*ns
                if (hi[s] != 1.0f) { blocking = true; hi[s] = 1.0f; }
                if (!solved && oo[s] != 0.0f) { blocking = true; oo[s] = 0.0f; }
            }

            unsigned long long chg = __ballot(blocking);
            if (tid == 9) {
                if (PHASE == 1 && solved) mask[t >> 5] |= (1u << (t & 31));
                if (chg == 0ull) {
                    // state is a fixed point: every future step repeats this selection
                    if (PHASE == 1 && solved) {
                        int w0 = t >> 5;
                        mask[w0] |= ~((1u << (t & 31)) - 1u);
                        for (int w = w0 + 1; w < 32; ++w) mask[w] = 0xFFFFFFFFu;
                    }
                    stop_sh = 1;
                }
            }
        }
        __syncthreads();
        if (stop_sh) break;
    }

    if (PHASE == 1) {
        if (tid < 32) sw[b * 32 + tid] = mask[tid];
    } else {
        // ---- hist output ----
        int i0 = tid * 4;
        float4 ho;
        ho.x = hi[i0]; ho.y = hi[i0 + 1]; ho.z = hi[i0 + 2]; ho.w = hi[i0 + 3];
        ((float4*)(out + b * HWC))[tid] = ho;

        // ---- backtrack: path starts as goal one-hot; reuse hh as path buffer ----
#pragma unroll
        for (int k = 0; k < 4; ++k) hh[i0 + k] = 0.0f;
        __syncthreads();
        if (tid == 0) {
            hh[goal] = 1.0f;
            int loc = (int)pp[goal];              // loc0 = par_i at goal (truncation)
            const int Tcur = Tend;                // current_t == T in both done/not-done cases
            for (int i2 = 0; i2 < Tcur; ++i2) {
                int w = (loc < 0) ? loc + HWC : loc;      // JAX wraps negatives once
                if (w >= 0 && w < HWC) hh[w] = 1.0f;      // scatter: OOB dropped
                int gidx = w < 0 ? 0 : (w > HWC - 1 ? HWC - 1 : w);  // gather: clamped
                loc = (int)pp[gidx];
            }
        }
        __syncthreads();
        float4 po;
        po.x = hh[i0]; po.y = hh[i0 + 1]; po.z = hh[i0 + 2]; po.w = hh[i0 + 3];
        ((float4*)(out + NB * HWC + b * HWC))[tid] = po;
    }
}

__global__ void dastar_reduce(const unsigned* __restrict__ sw, int* __restrict__ ctrl)
{
    __shared__ unsigned aw[32];
    int tid = threadIdx.x;
    if (tid < 32) {
        unsigned a = 0xFFFFFFFFu;
        for (int b = 0; b < NB; ++b) a &= sw[b * 32 + tid];
        aw[tid] = a;
    }
    __syncthreads();
    if (tid == 0) {
        int T = HWC - 1;                 // never all-solved: done=False, current_t = hw-1
        for (int w = 0; w < 32; ++w) {
            if (aw[w]) { T = w * 32 + (__ffs(aw[w]) - 1); break; }
        }
        ctrl[0] = T;
    }
}

extern "C" void kernel_launch(void* const* d_in, const int* in_sizes, int n_in,
                              void* d_out, int out_size, void* d_ws, size_t ws_size,
                              hipStream_t stream)
{
    const float* cm = (const float*)d_in[0];
    const float* sm = (const float*)d_in[1];
    const float* gm = (const float*)d_in[2];
    float* out = (float*)d_out;

    unsigned* sw  = (unsigned*)d_ws;                 // 32 batches * 32 words = 4 KiB
    int*      ctl = (int*)((char*)d_ws + 8192);

    dastar_sim<1><<<dim3(NB), dim3(256), 0, stream>>>(cm, sm, gm, sw, (const int*)nullptr, (float*)nullptr);
    dastar_reduce<<<dim3(1), dim3(64), 0, stream>>>(sw, ctl);
    dastar_sim<2><<<dim3(NB), dim3(256), 0, stream>>>(cm, sm, gm, sw, ctl, out);
}

// Round 2
// 1321.941 us; speedup vs baseline: 1.1848x; 1.1848x over previous
//
#include <hip/hip_runtime.h>
#include <math.h>

#define HWC 1024      // H*W
#define NB  32        // batch
#define GH  32
#define GW  32

__device__ __forceinline__ void combineMax(float& bv, int& bi, float ov, int oi) {
    // first-index-wins argmax combine
    if (ov > bv || (ov == bv && oi < bi)) { bv = ov; bi = oi; }
}

__device__ __forceinline__ float fe_expr(float g, float h, float o) {
    // EXACT expression chain of the reference: exp(-(g+h)*inv_c) * open, inv_c = 1/32
    return __fmul_rn(expf(__fmul_rn(__fadd_rn(g, h), -0.03125f)), o);
}

// Single wave (64 threads) per batch. All sync is intra-wave.
// PHASE 1: record per-step solved bits. PHASE 2: sim to ctrl[0], write hist+path.
template<int PHASE>
__global__ __launch_bounds__(64)
void dastar_sim(const float* __restrict__ cm_g, const float* __restrict__ sm_g,
                const float* __restrict__ gm_g, unsigned* __restrict__ sw,
                const int* __restrict__ ctrl, float* __restrict__ out)
{
    const int b   = blockIdx.x;
    const int tid = threadIdx.x;   // 0..63

    __shared__ __align__(16) float fe[HWC];   // cached f_exp per cell (also reused as path buffer)
    __shared__ __align__(16) float gg[HWC], oo[HWC], hi[HWC], cmS[HWC], hhS[HWC];
    __shared__ __align__(16) float pp[(PHASE == 2) ? HWC : 4];
    __shared__ int goal_sh;

    // ---- init: thread owns cells 16*tid..16*tid+15 via 4 float4 loads (coalesced) ----
    const float4* cm4 = (const float4*)(cm_g + b * HWC);
    const float4* sm4 = (const float4*)(sm_g + b * HWC);
    const float4* gm4 = (const float4*)(gm_g + b * HWC);
    float cmr[16], oor[16];
#pragma unroll
    for (int q = 0; q < 4; ++q) {
        int i4 = tid * 4 + q;          // float4 index; 256 per batch
        float4 c4 = cm4[i4];
        float4 s4 = sm4[i4];
        float4 g4 = gm4[i4];
        int base = i4 * 4;
        float cv[4] = {c4.x, c4.y, c4.z, c4.w};
        float sv[4] = {s4.x, s4.y, s4.z, s4.w};
        float gv[4] = {g4.x, g4.y, g4.z, g4.w};
#pragma unroll
        for (int j = 0; j < 4; ++j) {
            int i = base + j;
            cmr[q * 4 + j] = cv[j];
            oor[q * 4 + j] = sv[j];
            cmS[i] = cv[j];
            gg[i] = 0.0f;
            hi[i] = 0.0f;
            oo[i] = sv[j];
            if (gv[j] == 1.0f) goal_sh = i;   // unique goal
        }
    }
    __syncthreads();

    const int   goal = goal_sh;
    const float gy = (float)(goal >> 5), gx = (float)(goal & 31);
#pragma unroll
    for (int k = 0; k < 16; ++k) {
        int i = tid * 16 + k;
        float dy = (float)(i >> 5) - gy;
        float dx = (float)(i & 31) - gx;
        float h  = __fmul_rn(sqrtf(__fadd_rn(__fmul_rn(dy, dy), __fmul_rn(dx, dx))), cmr[k]);
        hhS[i] = h;
        fe[i]  = fe_expr(0.0f, h, oor[k]);   // g=0: add(0,h)==h exact
        if (PHASE == 2) pp[i] = (float)goal;
    }
    __syncthreads();

    const int Tend = (PHASE == 1) ? (HWC - 1) : ctrl[0];
    const int dyj = tid / 3 - 1, dxj = tid % 3 - 1;   // update-lane role (tid<9)
    unsigned word = 0u;                                // uniform solved-bit word

    for (int t = 0; t <= Tend; ++t) {
        // ---- argmax: register tree over 16 strided LDS reads (conflict-free) ----
        float bv; int bi;
        {
            float v[16];
#pragma unroll
            for (int k = 0; k < 16; ++k) v[k] = fe[tid + (k << 6)];
            float v8[8]; int i8[8];
#pragma unroll
            for (int k = 0; k < 8; ++k) {
                bool tk = v[2 * k + 1] > v[2 * k];
                v8[k] = tk ? v[2 * k + 1] : v[2 * k];
                i8[k] = tid + ((2 * k + (tk ? 1 : 0)) << 6);
            }
            float v4[4]; int i4a[4];
#pragma unroll
            for (int k = 0; k < 4; ++k) {
                bool tk = v8[2 * k + 1] > v8[2 * k];
                v4[k] = tk ? v8[2 * k + 1] : v8[2 * k];
                i4a[k] = tk ? i8[2 * k + 1] : i8[2 * k];
            }
            float v2[2]; int i2a[2];
#pragma unroll
            for (int k = 0; k < 2; ++k) {
                bool tk = v4[2 * k + 1] > v4[2 * k];
                v2[k] = tk ? v4[2 * k + 1] : v4[2 * k];
                i2a[k] = tk ? i4a[2 * k + 1] : i4a[2 * k];
            }
            bool tk = v2[1] > v2[0];
            bv = tk ? v2[1] : v2[0];
            bi = tk ? i2a[1] : i2a[0];
        }
        // ---- 64-lane butterfly (first-index tie-break) ----
#pragma unroll
        for (int m = 32; m >= 1; m >>= 1) {
            float ov = __shfl_xor(bv, m);
            int   oi = __shfl_xor(bi, m);
            combineMax(bv, bi, ov, oi);
        }
        const int  s      = bi;
        const bool solved = (s == goal);

        // ---- update lanes: 8 neighbors + center ----
        bool changed = false;
        if (tid < 9) {
            const int sy = s >> 5, sx = s & 31;
            if (tid == 4) {
                if (hi[s] != 1.0f) { hi[s] = 1.0f; changed = true; }
                if (!solved) {
                    float os = oo[s];
                    if (os != 0.0f) { oo[s] = 0.0f; fe[s] = 0.0f; changed = true; }
                }
            } else {
                int cy = sy + dyj, cx = sx + dxj;
                if (cy >= 0 && cy < GH && cx >= 0 && cx < GW) {
                    int   c  = (cy << 5) | cx;
                    float gs = gg[s];
                    float kc = (dyj != 0 && dxj != 0) ? 1.4142f : 1.0f;
                    float g2 = __fadd_rn(gs, kc);
                    float gc = gg[c], oc = oo[c], hc = hi[c], cmc = cmS[c];
                    float t1 = __fmul_rn(__fsub_rn(1.0f, oc), __fsub_rn(1.0f, hc));
                    float t2 = __fmul_rn(oc, (gc > g2) ? 1.0f : 0.0f);
                    float idxv = __fmul_rn(__fadd_rn(t1, t2), cmc);
                    if (idxv != 0.0f) {
                        changed = true;
                        float omi = __fsub_rn(1.0f, idxv);
                        float gn = __fadd_rn(__fmul_rn(g2, idxv), __fmul_rn(gc, omi));
                        float on = fminf(__fadd_rn(oc, idxv), 1.0f);
                        gg[c] = gn;
                        oo[c] = on;
                        fe[c] = fe_expr(gn, hhS[c], on);
                        if (PHASE == 2)
                            pp[c] = __fadd_rn(__fmul_rn((float)s, idxv), __fmul_rn(pp[c], omi));
                    }
                }
            }
        }
        unsigned long long chg = __ballot(changed);

        if (PHASE == 1) {
            if (solved) word |= (1u << (t & 31));
            if (chg == 0ull) {
                // fixed point: identical selection forever
                int widx = t >> 5;
                unsigned fill = solved ? 0xFFFFFFFFu : 0u;
                if (solved) word |= ~((1u << (t & 31)) - 1u);
                if (tid == 0) sw[b * 32 + widx] = word;
                for (int w = widx + 1 + tid; w < 32; w += 64) sw[b * 32 + w] = fill;
                break;
            }
            if ((t & 31) == 31) {
                if (tid == 0) sw[b * 32 + (t >> 5)] = word;
                word = 0u;
            }
        } else {
            if (chg == 0ull) break;   // state frozen; remaining steps are no-ops
        }
        __syncthreads();   // single-wave: cheap; orders LDS writes before next scan
    }
    __syncthreads();

    if (PHASE == 2) {
        // ---- hist output (float4, coalesced) ----
#pragma unroll
        for (int q = 0; q < 4; ++q) {
            int i4 = tid + (q << 6);
            ((float4*)(out + b * HWC))[i4] = ((const float4*)hi)[i4];
        }
        // ---- backtrack: path buffer reuses fe ----
#pragma unroll
        for (int q = 0; q < 4; ++q)
            ((float4*)fe)[tid + (q << 6)] = make_float4(0.f, 0.f, 0.f, 0.f);
        __syncthreads();
        if (tid == 0) {
            fe[goal] = 1.0f;
            int loc = (int)pp[goal];                      // trunc toward zero
            for (int i2 = 0; i2 < Tend; ++i2) {           // current_t == Tend
                int w = (loc < 0) ? loc + HWC : loc;      // JAX wraps negatives once
                if (w >= 0 && w < HWC) fe[w] = 1.0f;      // scatter: OOB dropped
                int gidx = w < 0 ? 0 : (w > HWC - 1 ? HWC - 1 : w);  // gather: clamped
                loc = (int)pp[gidx];
            }
        }
        __syncthreads();
#pragma unroll
        for (int q = 0; q < 4; ++q) {
            int i4 = tid + (q << 6);
            ((float4*)(out + NB * HWC + b * HWC))[i4] = ((const float4*)fe)[i4];
        }
    }
}

__global__ void dastar_reduce(const unsigned* __restrict__ sw, int* __restrict__ ctrl)
{
    __shared__ unsigned aw[32];
    int tid = threadIdx.x;
    if (tid < 32) {
        unsigned a = 0xFFFFFFFFu;
        for (int b = 0; b < NB; ++b) a &= sw[b * 32 + tid];
        aw[tid] = a;
    }
    __syncthreads();
    if (tid == 0) {
        int T = HWC - 1;                 // never all-solved: current_t = hw-1
        for (int w = 0; w < 32; ++w) {
            if (aw[w]) { T = w * 32 + (__ffs(aw[w]) - 1); break; }
        }
        ctrl[0] = T;
    }
}

extern "C" void kernel_launch(void* const* d_in, const int* in_sizes, int n_in,
                              void* d_out, int out_size, void* d_ws, size_t ws_size,
                              hipStream_t stream)
{
    const float* cm = (const float*)d_in[0];
    const float* sm = (const float*)d_in[1];
    const float* gm = (const float*)d_in[2];
    float* out = (float*)d_out;

    unsigned* sw  = (unsigned*)d_ws;                 // 32 batches * 32 words = 4 KiB
    int*      ctl = (int*)((char*)d_ws + 8192);

    dastar_sim<1><<<dim3(NB), dim3(64), 0, stream>>>(cm, sm, gm, sw, (const int*)nullptr, (float*)nullptr);
    dastar_reduce<<<dim3(1), dim3(64), 0, stream>>>(sw, ctl);
    dastar_sim<2><<<dim3(NB), dim3(64), 0, stream>>>(cm, sm, gm, sw, ctl, out);
}

// Round 3
// 327.387 us; speedup vs baseline: 4.7841x; 4.0379x over previous
//
#include <hip/hip_runtime.h>
#include <math.h>

#define HWC 1024      // H*W
#define NB  32        // batch
#define GH  32
#define GW  32
#define CH  128       // steps per phase-1 chunk
#define NCH (HWC / CH)

// d_ws layout (bytes)
#define WS_SW    0                         // u32 sw[NB][32] solved-bit words
#define WS_CTL   4096                      // int ctl[2] = {tstar, found}
#define WS_STAT  4160                      // int status[NB]: 0=running 1=frozen-solved 2=frozen-unsolved
#define WS_STATE 8192                      // float state[NB][4][HWC]: gg,oo,hi,fe
#define WS_NEED  (WS_STATE + (size_t)NB * 4 * HWC * 4)

__device__ __forceinline__ void combineMax(float& bv, int& bi, float ov, int oi) {
    if (ov > bv || (ov == bv && oi < bi)) { bv = ov; bi = oi; }
}

__device__ __forceinline__ float fe_expr(float g, float h, float o) {
    // EXACT reference chain: exp(-(g+h)*inv_c) * open, inv_c = 1/32 (exact scale)
    return __fmul_rn(expf(__fmul_rn(__fadd_rn(g, h), -0.03125f)), o);
}

// ---------- phase-1 chunk: sim steps [t0, t0+nsteps), record solved bits ----------
__global__ __launch_bounds__(64)
void dastar_p1(const float* __restrict__ cm_g, const float* __restrict__ sm_g,
               const float* __restrict__ gm_g, unsigned* __restrict__ sw,
               int* __restrict__ ctl, float* __restrict__ state,
               int* __restrict__ status, int t0, int nsteps)
{
    const int b   = blockIdx.x;
    const int tid = threadIdx.x;   // 0..63
    const int tend = t0 + nsteps;
    const bool chunked = (tend < HWC);   // legacy monolithic pass never touches state/status

    if (t0 == 0) {
        if (b == 0 && tid == 0) { ctl[0] = HWC - 1; ctl[1] = 0; }
    } else {
        if (ctl[1]) return;                       // t* already found globally
        int st = status[b];
        if (st) {                                 // batch frozen in earlier chunk
            unsigned fill = (st == 1) ? 0xFFFFFFFFu : 0u;
            for (int w = (t0 >> 5) + tid; w < (tend >> 5); w += 64) sw[b * 32 + w] = fill;
            return;
        }
    }

    __shared__ __align__(16) float fe[HWC], gg[HWC], oo[HWC], hi[HWC], cmS[HWC], hhS[HWC];
    __shared__ int goal_sh;

    const float4* cm4 = (const float4*)(cm_g + b * HWC);
    const float4* sm4 = (const float4*)(sm_g + b * HWC);
    const float4* gm4 = (const float4*)(gm_g + b * HWC);
    float* stb = state + (size_t)b * 4 * HWC;

    float cmr[16], oor[16];
#pragma unroll
    for (int q = 0; q < 4; ++q) {
        int i4 = tid * 4 + q;
        float4 c4 = cm4[i4];
        float4 g4 = gm4[i4];
        int base = i4 * 4;
        float cv[4] = {c4.x, c4.y, c4.z, c4.w};
        float gv[4] = {g4.x, g4.y, g4.z, g4.w};
        if (t0 == 0) {
            float4 s4 = sm4[i4];
            float sv[4] = {s4.x, s4.y, s4.z, s4.w};
#pragma unroll
            for (int j = 0; j < 4; ++j) { oor[q * 4 + j] = sv[j]; }
#pragma unroll
            for (int j = 0; j < 4; ++j) {
                int i = base + j;
                gg[i] = 0.0f; hi[i] = 0.0f; oo[i] = sv[j];
            }
        }
#pragma unroll
        for (int j = 0; j < 4; ++j) {
            int i = base + j;
            cmr[q * 4 + j] = cv[j];
            cmS[i] = cv[j];
            if (gv[j] == 1.0f) goal_sh = i;
        }
    }
    if (t0 > 0) {   // bitwise state restore → identical trajectory to monolithic
        const float4* s4p = (const float4*)stb;
#pragma unroll
        for (int q = 0; q < 4; ++q) {
            int i4 = tid + (q << 6);
            ((float4*)gg)[i4] = s4p[i4];
            ((float4*)oo)[i4] = s4p[256 + i4];
            ((float4*)hi)[i4] = s4p[512 + i4];
            ((float4*)fe)[i4] = s4p[768 + i4];
        }
    }
    __syncthreads();

    const int   goal = goal_sh;
    const float gy = (float)(goal >> 5), gx = (float)(goal & 31);
#pragma unroll
    for (int k = 0; k < 16; ++k) {
        int i = tid * 16 + k;
        float dy = (float)(i >> 5) - gy;
        float dx = (float)(i & 31) - gx;
        float h  = __fmul_rn(sqrtf(__fadd_rn(__fmul_rn(dy, dy), __fmul_rn(dx, dx))), cmr[k]);
        hhS[i] = h;
        if (t0 == 0) fe[i] = fe_expr(0.0f, h, oor[k]);
    }
    __syncthreads();

    const int dyj = tid / 3 - 1, dxj = tid % 3 - 1;
    unsigned word = 0u;
    bool frozen = false;

    for (int t = t0; t < tend; ++t) {
        // ---- argmax over fe (strided, conflict-free) ----
        float bv; int bi;
        {
            float v[16];
#pragma unroll
            for (int k = 0; k < 16; ++k) v[k] = fe[tid + (k << 6)];
            float v8[8]; int i8[8];
#pragma unroll
            for (int k = 0; k < 8; ++k) {
                bool tk = v[2 * k + 1] > v[2 * k];
                v8[k] = tk ? v[2 * k + 1] : v[2 * k];
                i8[k] = tid + ((2 * k + (tk ? 1 : 0)) << 6);
            }
            float v4[4]; int i4a[4];
#pragma unroll
            for (int k = 0; k < 4; ++k) {
                bool tk = v8[2 * k + 1] > v8[2 * k];
                v4[k] = tk ? v8[2 * k + 1] : v8[2 * k];
                i4a[k] = tk ? i8[2 * k + 1] : i8[2 * k];
            }
            float v2[2]; int i2a[2];
#pragma unroll
            for (int k = 0; k < 2; ++k) {
                bool tk = v4[2 * k + 1] > v4[2 * k];
                v2[k] = tk ? v4[2 * k + 1] : v4[2 * k];
                i2a[k] = tk ? i4a[2 * k + 1] : i4a[2 * k];
            }
            bool tk = v2[1] > v2[0];
            bv = tk ? v2[1] : v2[0];
            bi = tk ? i2a[1] : i2a[0];
        }
#pragma unroll
        for (int m = 32; m >= 1; m >>= 1) {
            float ov = __shfl_xor(bv, m);
            int   oi = __shfl_xor(bi, m);
            combineMax(bv, bi, ov, oi);
        }
        const int  s      = bi;
        const bool solved = (s == goal);

        bool changed = false;
        if (tid < 9) {
            const int sy = s >> 5, sx = s & 31;
            if (tid == 4) {
                if (hi[s] != 1.0f) { hi[s] = 1.0f; changed = true; }
                if (!solved && oo[s] != 0.0f) { oo[s] = 0.0f; fe[s] = 0.0f; changed = true; }
            } else {
                int cy = sy + dyj, cx = sx + dxj;
                if (cy >= 0 && cy < GH && cx >= 0 && cx < GW) {
                    int   c  = (cy << 5) | cx;
                    float g2 = __fadd_rn(gg[s], (dyj != 0 && dxj != 0) ? 1.4142f : 1.0f);
                    float gc = gg[c], oc = oo[c], hc = hi[c], cmc = cmS[c];
                    float t1 = __fmul_rn(__fsub_rn(1.0f, oc), __fsub_rn(1.0f, hc));
                    float t2 = __fmul_rn(oc, (gc > g2) ? 1.0f : 0.0f);
                    float idxv = __fmul_rn(__fadd_rn(t1, t2), cmc);
                    if (idxv != 0.0f) {
                        changed = true;
                        float omi = __fsub_rn(1.0f, idxv);
                        float gn = __fadd_rn(__fmul_rn(g2, idxv), __fmul_rn(gc, omi));
                        float on = fminf(__fadd_rn(oc, idxv), 1.0f);
                        gg[c] = gn; oo[c] = on;
                        fe[c] = fe_expr(gn, hhS[c], on);
                    }
                }
            }
        }
        unsigned long long chg = __ballot(changed);

        if (solved) word |= (1u << (t & 31));
        if (chg == 0ull) {
            // fixed point: identical selection forever
            int widx = t >> 5;
            if (solved) word |= ~((1u << (t & 31)) - 1u);
            if (tid == 0) sw[b * 32 + widx] = word;
            unsigned fill = solved ? 0xFFFFFFFFu : 0u;
            for (int w = widx + 1 + tid; w < (tend >> 5); w += 64) sw[b * 32 + w] = fill;
            if (tid == 0 && chunked) status[b] = solved ? 1 : 2;
            frozen = true;
            break;
        }
        if ((t & 31) == 31) {
            if (tid == 0) sw[b * 32 + (t >> 5)] = word;
            word = 0u;
        }
        __syncthreads();
    }

    if (!frozen && chunked) {
        if (tid == 0) status[b] = 0;
        float4* s4p = (float4*)stb;
#pragma unroll
        for (int q = 0; q < 4; ++q) {
            int i4 = tid + (q << 6);
            s4p[i4]       = ((const float4*)gg)[i4];
            s4p[256 + i4] = ((const float4*)oo)[i4];
            s4p[512 + i4] = ((const float4*)hi)[i4];
            s4p[768 + i4] = ((const float4*)fe)[i4];
        }
    }
}

// ---------- AND-reduce one chunk's solved bits; latch first t* ----------
__global__ void dastar_reduce(const unsigned* __restrict__ sw, int* __restrict__ ctl,
                              int w0, int nw)
{
    if (ctl[1]) return;
    __shared__ unsigned aw[32];
    int tid = threadIdx.x;
    if (tid < nw) {
        unsigned a = 0xFFFFFFFFu;
        for (int b = 0; b < NB; ++b) a &= sw[b * 32 + w0 + tid];
        aw[tid] = a;
    }
    __syncthreads();
    if (tid == 0) {
        for (int w = 0; w < nw; ++w) {
            if (aw[w]) { ctl[0] = (w0 + w) * 32 + (__ffs(aw[w]) - 1); ctl[1] = 1; break; }
        }
    }
}

// ---------- phase 2: sim 0..t* with parents, write hist + path ----------
__global__ __launch_bounds__(64)
void dastar_p2(const float* __restrict__ cm_g, const float* __restrict__ sm_g,
               const float* __restrict__ gm_g, const int* __restrict__ ctl,
               float* __restrict__ out)
{
    const int b   = blockIdx.x;
    const int tid = threadIdx.x;

    __shared__ __align__(16) float fe[HWC], gg[HWC], oo[HWC], hi[HWC], cmS[HWC], hhS[HWC], pp[HWC];
    __shared__ int goal_sh;

    const float4* cm4 = (const float4*)(cm_g + b * HWC);
    const float4* sm4 = (const float4*)(sm_g + b * HWC);
    const float4* gm4 = (const float4*)(gm_g + b * HWC);
    float cmr[16], oor[16];
#pragma unroll
    for (int q = 0; q < 4; ++q) {
        int i4 = tid * 4 + q;
        float4 c4 = cm4[i4];
        float4 s4 = sm4[i4];
        float4 g4 = gm4[i4];
        int base = i4 * 4;
        float cv[4] = {c4.x, c4.y, c4.z, c4.w};
        float sv[4] = {s4.x, s4.y, s4.z, s4.w};
        float gv[4] = {g4.x, g4.y, g4.z, g4.w};
#pragma unroll
        for (int j = 0; j < 4; ++j) {
            int i = base + j;
            cmr[q * 4 + j] = cv[j];
            oor[q * 4 + j] = sv[j];
            cmS[i] = cv[j];
            gg[i] = 0.0f; hi[i] = 0.0f; oo[i] = sv[j];
            if (gv[j] == 1.0f) goal_sh = i;
        }
    }
    __syncthreads();

    const int   goal = goal_sh;
    const float gy = (float)(goal >> 5), gx = (float)(goal & 31);
#pragma unroll
    for (int k = 0; k < 16; ++k) {
        int i = tid * 16 + k;
        float dy = (float)(i >> 5) - gy;
        float dx = (float)(i & 31) - gx;
        float h  = __fmul_rn(sqrtf(__fadd_rn(__fmul_rn(dy, dy), __fmul_rn(dx, dx))), cmr[k]);
        hhS[i] = h;
        fe[i]  = fe_expr(0.0f, h, oor[k]);
        pp[i]  = (float)goal;
    }
    __syncthreads();

    const int Tend = ctl[0];
    const int dyj = tid / 3 - 1, dxj = tid % 3 - 1;

    for (int t = 0; t <= Tend; ++t) {
        float bv; int bi;
        {
            float v[16];
#pragma unroll
            for (int k = 0; k < 16; ++k) v[k] = fe[tid + (k << 6)];
            float v8[8]; int i8[8];
#pragma unroll
            for (int k = 0; k < 8; ++k) {
                bool tk = v[2 * k + 1] > v[2 * k];
                v8[k] = tk ? v[2 * k + 1] : v[2 * k];
                i8[k] = tid + ((2 * k + (tk ? 1 : 0)) << 6);
            }
            float v4[4]; int i4a[4];
#pragma unroll
            for (int k = 0; k < 4; ++k) {
                bool tk = v8[2 * k + 1] > v8[2 * k];
                v4[k] = tk ? v8[2 * k + 1] : v8[2 * k];
                i4a[k] = tk ? i8[2 * k + 1] : i8[2 * k];
            }
            float v2[2]; int i2a[2];
#pragma unroll
            for (int k = 0; k < 2; ++k) {
                bool tk = v4[2 * k + 1] > v4[2 * k];
                v2[k] = tk ? v4[2 * k + 1] : v4[2 * k];
                i2a[k] = tk ? i4a[2 * k + 1] : i4a[2 * k];
            }
            bool tk = v2[1] > v2[0];
            bv = tk ? v2[1] : v2[0];
            bi = tk ? i2a[1] : i2a[0];
        }
#pragma unroll
        for (int m = 32; m >= 1; m >>= 1) {
            float ov = __shfl_xor(bv, m);
            int   oi = __shfl_xor(bi, m);
            combineMax(bv, bi, ov, oi);
        }
        const int  s      = bi;
        const bool solved = (s == goal);

        bool changed = false;
        if (tid < 9) {
            const int sy = s >> 5, sx = s & 31;
            if (tid == 4) {
                if (hi[s] != 1.0f) { hi[s] = 1.0f; changed = true; }
                if (!solved && oo[s] != 0.0f) { oo[s] = 0.0f; fe[s] = 0.0f; changed = true; }
            } else {
                int cy = sy + dyj, cx = sx + dxj;
                if (cy >= 0 && cy < GH && cx >= 0 && cx < GW) {
                    int   c  = (cy << 5) | cx;
                    float g2 = __fadd_rn(gg[s], (dyj != 0 && dxj != 0) ? 1.4142f : 1.0f);
                    float gc = gg[c], oc = oo[c], hc = hi[c], cmc = cmS[c];
                    float t1 = __fmul_rn(__fsub_rn(1.0f, oc), __fsub_rn(1.0f, hc));
                    float t2 = __fmul_rn(oc, (gc > g2) ? 1.0f : 0.0f);
                    float idxv = __fmul_rn(__fadd_rn(t1, t2), cmc);
                    if (idxv != 0.0f) {
                        changed = true;
                        float omi = __fsub_rn(1.0f, idxv);
                        float gn = __fadd_rn(__fmul_rn(g2, idxv), __fmul_rn(gc, omi));
                        float on = fminf(__fadd_rn(oc, idxv), 1.0f);
                        gg[c] = gn; oo[c] = on;
                        fe[c] = fe_expr(gn, hhS[c], on);
                        pp[c] = __fadd_rn(__fmul_rn((float)s, idxv), __fmul_rn(pp[c], omi));
                    }
                }
            }
        }
        unsigned long long chg = __ballot(changed);
        if (chg == 0ull) break;   // state frozen; remaining steps are identity
        __syncthreads();
    }
    __syncthreads();

    // ---- hist output ----
#pragma unroll
    for (int q = 0; q < 4; ++q) {
        int i4 = tid + (q << 6);
        ((float4*)(out + b * HWC))[i4] = ((const float4*)hi)[i4];
    }
    // ---- backtrack (path buffer reuses fe) ----
#pragma unroll
    for (int q = 0; q < 4; ++q)
        ((float4*)fe)[tid + (q << 6)] = make_float4(0.f, 0.f, 0.f, 0.f);
    __syncthreads();
    if (tid == 0) {
        const int Tcur = Tend;
        fe[goal] = 1.0f;
        int loc = (int)pp[goal];
        for (int i2 = 0; i2 < Tcur; ++i2) {
            int w = (loc < 0) ? loc + HWC : loc;          // JAX wraps negatives once
            if (w >= 0 && w < HWC) {
                if (fe[w] == 1.0f) break;                 // revisit: pointer chase cycles, no new cells
                fe[w] = 1.0f;
            }
            int gidx = w < 0 ? 0 : (w > HWC - 1 ? HWC - 1 : w);
            loc = (int)pp[gidx];
        }
    }
    __syncthreads();
#pragma unroll
    for (int q = 0; q < 4; ++q) {
        int i4 = tid + (q << 6);
        ((float4*)(out + NB * HWC + b * HWC))[i4] = ((const float4*)fe)[i4];
    }
}

extern "C" void kernel_launch(void* const* d_in, const int* in_sizes, int n_in,
                              void* d_out, int out_size, void* d_ws, size_t ws_size,
                              hipStream_t stream)
{
    const float* cm = (const float*)d_in[0];
    const float* sm = (const float*)d_in[1];
    const float* gm = (const float*)d_in[2];
    float* out = (float*)d_out;

    unsigned* sw    = (unsigned*)d_ws;
    int*      ctl   = (int*)((char*)d_ws + WS_CTL);
    int*      stat  = (int*)((char*)d_ws + WS_STAT);
    float*    state = (float*)((char*)d_ws + WS_STATE);

    if (ws_size >= WS_NEED) {
        for (int k = 0; k < NCH; ++k) {
            dastar_p1<<<dim3(NB), dim3(64), 0, stream>>>(cm, sm, gm, sw, ctl, state, stat, k * CH, CH);
            dastar_reduce<<<dim3(1), dim3(64), 0, stream>>>(sw, ctl, k * (CH / 32), CH / 32);
        }
    } else {
        dastar_p1<<<dim3(NB), dim3(64), 0, stream>>>(cm, sm, gm, sw, ctl, state, stat, 0, HWC);
        dastar_reduce<<<dim3(1), dim3(64), 0, stream>>>(sw, ctl, 0, 32);
    }
    dastar_p2<<<dim3(NB), dim3(64), 0, stream>>>(cm, sm, gm, ctl, out);
}

// Round 4
// 198.372 us; speedup vs baseline: 7.8955x; 1.6504x over previous
//
#include <hip/hip_runtime.h>
#include <math.h>

#define HWC 1024      // H*W
#define NB  32        // batch
#define GH  32
#define GW  32
#define CH  128       // steps per phase-1 chunk (fast path)
#define NCH (HWC / CH)

// d_ws layout (bytes)
#define WS_SW      0                        // u32 sw[NB][32] solved-bit words
#define WS_CTL     4096                     // int ctl[2] = {tstar, found}
#define WS_STAT    4160                     // int status[NB]
#define WS_LOGEND  4416                     // int logend[NB]
#define WS_STATE   8192                     // float state[NB][4][HWC]: gg,oo,hi,fe
#define WS_LOG     (WS_STATE + (size_t)NB * 4 * HWC * 4)          // u32 log[NB][HWC][9]
#define WS_NEED_R3 (WS_STATE + (size_t)NB * 4 * HWC * 4)
#define WS_NEED_FAST (WS_LOG + (size_t)NB * HWC * 9 * 4)

__device__ __forceinline__ void combineMax(float& bv, int& bi, float ov, int oi) {
    if (ov > bv || (ov == bv && oi < bi)) { bv = ov; bi = oi; }
}

__device__ __forceinline__ float fe_expr(float g, float h, float o) {
    // EXACT reference chain: exp(-(g+h)*inv_c) * open, inv_c = 1/32 (exact scale)
    return __fmul_rn(expf(__fmul_rn(__fadd_rn(g, h), -0.03125f)), o);
}

// ---------------- phase-1 chunk ----------------
// LOGON=1: fast path (chunk size CH, LDS-buffered sw words, per-step log, folded reduce)
// LOGON=0: legacy path (any nsteps, direct sw stores, no log)
template<int LOGON>
__global__ __launch_bounds__(64)
void dastar_p1(const float* __restrict__ cm_g, const float* __restrict__ sm_g,
               const float* __restrict__ gm_g, unsigned* __restrict__ sw,
               int* __restrict__ ctl, float* __restrict__ state,
               int* __restrict__ status, unsigned* __restrict__ logg,
               int* __restrict__ logend, int t0, int nsteps)
{
    const int b   = blockIdx.x;
    const int tid = threadIdx.x;   // 0..63
    const int tend = t0 + nsteps;
    const bool chunked = (tend < HWC) || LOGON;

    __shared__ __align__(16) float fe[HWC], gg[HWC], oo[HWC], hi[HWC], cmS[HWC], hhS[HWC];
    __shared__ unsigned slog[CH * 9];
    __shared__ unsigned swbuf[4];
    __shared__ unsigned aw[4];
    __shared__ int fnd;
    __shared__ int goal_sh;

    if (t0 == 0) {
        if (b == 0 && tid == 0) { ctl[0] = HWC - 1; ctl[1] = 0; }
    } else {
        if (ctl[1]) return;                  // t* latched in an earlier chunk
        if (LOGON) {
            // folded reduce of the previous chunk (all blocks redundantly)
            const int w0 = (t0 - CH) >> 5;
            if (tid < 4) {
                unsigned a = 0xFFFFFFFFu;
                for (int bb = 0; bb < NB; ++bb) a &= sw[bb * 32 + w0 + tid];
                aw[tid] = a;
            }
            if (tid == 0) fnd = 0;
            __syncthreads();
            if (tid == 0) {
                for (int w = 0; w < 4; ++w) {
                    if (aw[w]) {
                        ctl[0] = (w0 + w) * 32 + (__ffs(aw[w]) - 1);
                        ctl[1] = 1; fnd = 1; break;
                    }
                }
            }
            __syncthreads();
            if (fnd) return;
        }
        int st = status[b];
        if (st) {                            // batch frozen in an earlier chunk
            unsigned fill = (st == 1) ? 0xFFFFFFFFu : 0u;
            for (int w = (t0 >> 5) + tid; w < (tend >> 5); w += 64) sw[b * 32 + w] = fill;
            return;
        }
    }

    const float4* cm4 = (const float4*)(cm_g + b * HWC);
    const float4* sm4 = (const float4*)(sm_g + b * HWC);
    const float4* gm4 = (const float4*)(gm_g + b * HWC);
    float* stb = state + (size_t)b * 4 * HWC;

    float cmr[16], oor[16];
#pragma unroll
    for (int q = 0; q < 4; ++q) {
        int i4 = tid * 4 + q;
        float4 c4 = cm4[i4];
        float4 g4 = gm4[i4];
        int base = i4 * 4;
        float cv[4] = {c4.x, c4.y, c4.z, c4.w};
        float gv[4] = {g4.x, g4.y, g4.z, g4.w};
        if (t0 == 0) {
            float4 s4 = sm4[i4];
            float sv[4] = {s4.x, s4.y, s4.z, s4.w};
#pragma unroll
            for (int j = 0; j < 4; ++j) {
                int i = base + j;
                oor[q * 4 + j] = sv[j];
                gg[i] = 0.0f; hi[i] = 0.0f; oo[i] = sv[j];
            }
        }
#pragma unroll
        for (int j = 0; j < 4; ++j) {
            int i = base + j;
            cmr[q * 4 + j] = cv[j];
            cmS[i] = cv[j];
            if (gv[j] == 1.0f) goal_sh = i;
        }
    }
    if (t0 > 0) {   // bitwise state restore → identical trajectory to monolithic
        const float4* s4p = (const float4*)stb;
#pragma unroll
        for (int q = 0; q < 4; ++q) {
            int i4 = tid + (q << 6);
            ((float4*)gg)[i4] = s4p[i4];
            ((float4*)oo)[i4] = s4p[256 + i4];
            ((float4*)hi)[i4] = s4p[512 + i4];
            ((float4*)fe)[i4] = s4p[768 + i4];
        }
    }
    __syncthreads();

    const int   goal = goal_sh;
    const float gy = (float)(goal >> 5), gx = (float)(goal & 31);
#pragma unroll
    for (int k = 0; k < 16; ++k) {
        int i = tid * 16 + k;
        float dy = (float)(i >> 5) - gy;
        float dx = (float)(i & 31) - gx;
        float h  = __fmul_rn(sqrtf(__fadd_rn(__fmul_rn(dy, dy), __fmul_rn(dx, dx))), cmr[k]);
        hhS[i] = h;
        if (t0 == 0) fe[i] = fe_expr(0.0f, h, oor[k]);
    }
    __syncthreads();

    const int dyj = tid / 3 - 1, dxj = tid % 3 - 1;
    unsigned word = 0u;
    bool frozen = false, fsolved = false;
    int  fstep = 0;

    for (int t = t0; t < tend; ++t) {
        // ---- argmax over fe: blocked ownership, 4x ds_read_b128 ----
        float bv; int bi;
        {
            float v[16];
            const float4* fe4 = (const float4*)fe;
#pragma unroll
            for (int q = 0; q < 4; ++q) {
                float4 x = fe4[tid * 4 + q];
                v[q * 4]     = x.x; v[q * 4 + 1] = x.y;
                v[q * 4 + 2] = x.z; v[q * 4 + 3] = x.w;
            }
            const int cbase = tid * 16;
            float v8[8]; int i8[8];
#pragma unroll
            for (int k = 0; k < 8; ++k) {
                bool tk = v[2 * k + 1] > v[2 * k];
                v8[k] = tk ? v[2 * k + 1] : v[2 * k];
                i8[k] = cbase + 2 * k + (tk ? 1 : 0);
            }
            float v4[4]; int i4a[4];
#pragma unroll
            for (int k = 0; k < 4; ++k) {
                bool tk = v8[2 * k + 1] > v8[2 * k];
                v4[k] = tk ? v8[2 * k + 1] : v8[2 * k];
                i4a[k] = tk ? i8[2 * k + 1] : i8[2 * k];
            }
            float v2[2]; int i2a[2];
#pragma unroll
            for (int k = 0; k < 2; ++k) {
                bool tk = v4[2 * k + 1] > v4[2 * k];
                v2[k] = tk ? v4[2 * k + 1] : v4[2 * k];
                i2a[k] = tk ? i4a[2 * k + 1] : i4a[2 * k];
            }
            bool tk = v2[1] > v2[0];
            bv = tk ? v2[1] : v2[0];
            bi = tk ? i2a[1] : i2a[0];
        }
#pragma unroll
        for (int m = 32; m >= 1; m >>= 1) {
            float ov = __shfl_xor(bv, m);
            int   oi = __shfl_xor(bi, m);
            combineMax(bv, bi, ov, oi);
        }
        const int  s      = bi;
        const bool solved = (s == goal);

        bool changed = false;
        float lidx = 0.0f;
        if (tid < 9) {
            const int sy = s >> 5, sx = s & 31;
            if (tid == 4) {
                if (hi[s] != 1.0f) { hi[s] = 1.0f; changed = true; }
                if (!solved && oo[s] != 0.0f) { oo[s] = 0.0f; fe[s] = 0.0f; changed = true; }
            } else {
                int cy = sy + dyj, cx = sx + dxj;
                if (cy >= 0 && cy < GH && cx >= 0 && cx < GW) {
                    int   c  = (cy << 5) | cx;
                    float g2 = __fadd_rn(gg[s], (dyj != 0 && dxj != 0) ? 1.4142f : 1.0f);
                    float gc = gg[c], oc = oo[c], hc = hi[c], cmc = cmS[c];
                    float t1 = __fmul_rn(__fsub_rn(1.0f, oc), __fsub_rn(1.0f, hc));
                    float t2 = __fmul_rn(oc, (gc > g2) ? 1.0f : 0.0f);
                    float idxv = __fmul_rn(__fadd_rn(t1, t2), cmc);
                    lidx = idxv;                          // blend with idxv==0 is exact identity
                    if (idxv != 0.0f) {
                        changed = true;
                        float omi = __fsub_rn(1.0f, idxv);
                        float gn = __fadd_rn(__fmul_rn(g2, idxv), __fmul_rn(gc, omi));
                        float on = fminf(__fadd_rn(oc, idxv), 1.0f);
                        gg[c] = gn; oo[c] = on;
                        fe[c] = fe_expr(gn, hhS[c], on);
                    }
                }
            }
            if (LOGON) slog[(t - t0) * 9 + tid] = (tid == 4) ? (unsigned)s : __float_as_uint(lidx);
        }
        unsigned long long chg = __ballot(changed);

        if (solved) word |= (1u << (t & 31));
        if (chg == 0ull) {
            // fixed point: identical selection forever
            if (solved) word |= ~((1u << (t & 31)) - 1u);
            unsigned fill = solved ? 0xFFFFFFFFu : 0u;
            if (LOGON) {
                int widx = (t >> 5) - (t0 >> 5);
                if (tid == 0) {
                    swbuf[widx] = word;
                    for (int w = widx + 1; w < 4; ++w) swbuf[w] = fill;
                }
            } else {
                int widx = t >> 5;
                if (tid == 0) sw[b * 32 + widx] = word;
                for (int w = widx + 1 + tid; w < (tend >> 5); w += 64) sw[b * 32 + w] = fill;
            }
            frozen = true; fsolved = solved; fstep = t;
            break;
        }
        if ((t & 31) == 31) {
            if (tid == 0) {
                if (LOGON) swbuf[(t >> 5) - (t0 >> 5)] = word;
                else       sw[b * 32 + (t >> 5)] = word;
            }
            word = 0u;
        }
        __syncthreads();
    }
    __syncthreads();

    const int tstop = frozen ? (fstep + 1) : tend;
    if (LOGON) {
        if (tid < 4) sw[b * 32 + (t0 >> 5) + tid] = swbuf[tid];
        const int nrow = (tstop - t0) * 9;
        unsigned* lgb = logg + ((size_t)b * HWC + t0) * 9;
        for (int idx = tid; idx < nrow; idx += 64) lgb[idx] = slog[idx];
        if (tid == 0) logend[b] = tstop - 1;
    }
    if (chunked) {
        if (frozen) {
            if (tid == 0) status[b] = fsolved ? 1 : 2;
        } else {
            if (tid == 0) status[b] = 0;
            float4* s4p = (float4*)stb;
#pragma unroll
            for (int q = 0; q < 4; ++q) {
                int i4 = tid + (q << 6);
                s4p[i4]       = ((const float4*)gg)[i4];
                s4p[256 + i4] = ((const float4*)oo)[i4];
                s4p[512 + i4] = ((const float4*)hi)[i4];
                s4p[768 + i4] = ((const float4*)fe)[i4];
            }
        }
    }
}

// ---------------- log-driven phase 2 (fast path) ----------------
__global__ __launch_bounds__(64)
void dastar_p2her(const float* __restrict__ gm_g, const unsigned* __restrict__ sw,
                  const int* __restrict__ ctl, const unsigned* __restrict__ logg,
                  const int* __restrict__ logend, float* __restrict__ out)
{
    const int b   = blockIdx.x;
    const int tid = threadIdx.x;

    __shared__ __align__(16) float pp[HWC], hi[HWC], pb[HWC];
    __shared__ unsigned slog[HWC * 9 / 1];   // 36.9 KB
    __shared__ int goal_sh, ts_sh;

    // goal
    const float4* gm4 = (const float4*)(gm_g + b * HWC);
#pragma unroll
    for (int q = 0; q < 4; ++q) {
        float4 g4 = gm4[tid * 4 + q];
        int base = (tid * 4 + q) * 4;
        if (g4.x == 1.0f) goal_sh = base;
        if (g4.y == 1.0f) goal_sh = base + 1;
        if (g4.z == 1.0f) goal_sh = base + 2;
        if (g4.w == 1.0f) goal_sh = base + 3;
    }
    // t*
    if (tid == 0) {
        int tstar;
        if (ctl[1]) tstar = ctl[0];
        else {
            tstar = HWC - 1;                 // chunks 0..6 were reduced; check chunk 7 here
            for (int w = 28; w < 32; ++w) {
                unsigned a = 0xFFFFFFFFu;
                for (int bb = 0; bb < NB; ++bb) a &= sw[bb * 32 + w];
                if (a) { tstar = w * 32 + (__ffs(a) - 1); break; }
            }
        }
        ts_sh = tstar;
    }
    __syncthreads();
    const int goal  = goal_sh;
    const int tstar = ts_sh;
    const int Tl    = min(tstar, logend[b]);

    // preload log rows 0..Tl
    const unsigned* lgb = logg + (size_t)b * HWC * 9;
    const int n = (Tl + 1) * 9;
    for (int idx = tid; idx < n; idx += 64) slog[idx] = lgb[idx];
    const float goalf = (float)goal;
#pragma unroll
    for (int k = 0; k < 16; ++k) {
        int i = tid * 16 + k;
        hi[i] = 0.0f; pp[i] = goalf; pb[i] = 0.0f;
    }
    __syncthreads();

    // hist = union of selected cells, t <= Tl (selection is constant/no-op past a freeze)
    for (int t = tid; t <= Tl; t += 64) hi[slog[t * 9 + 4]] = 1.0f;
    __syncthreads();
#pragma unroll
    for (int q = 0; q < 4; ++q) {
        int i4 = tid + (q << 6);
        ((float4*)(out + b * HWC))[i4] = ((const float4*)hi)[i4];
    }

    // parents replay: 8 neighbor lanes, sequential over t (exact blend chain)
    if (tid < 9 && tid != 4) {
        const int dyj = tid / 3 - 1, dxj = tid % 3 - 1;
        for (int t = 0; t <= Tl; ++t) {
            float idxv = __uint_as_float(slog[t * 9 + tid]);
            if (idxv != 0.0f) {
                int   su = (int)slog[t * 9 + 4];
                int   c  = su + (dyj << 5) + dxj;    // idxv!=0 implies in-bounds
                float omi = __fsub_rn(1.0f, idxv);
                pp[c] = __fadd_rn(__fmul_rn((float)su, idxv), __fmul_rn(pp[c], omi));
            }
        }
    }
    __syncthreads();

    // backtrack
    if (tid == 0) {
        pb[goal] = 1.0f;
        int loc = (int)pp[goal];
        for (int i2 = 0; i2 < tstar; ++i2) {
            int w = (loc < 0) ? loc + HWC : loc;              // JAX wraps negatives once
            if (w >= 0 && w < HWC) {
                if (pb[w] == 1.0f) break;                     // revisit: chase cycles, no new cells
                pb[w] = 1.0f;
            }
            int gidx = w < 0 ? 0 : (w > HWC - 1 ? HWC - 1 : w);
            loc = (int)pp[gidx];
        }
    }
    __syncthreads();
#pragma unroll
    for (int q = 0; q < 4; ++q) {
        int i4 = tid + (q << 6);
        ((float4*)(out + NB * HWC + b * HWC))[i4] = ((const float4*)pb)[i4];
    }
}

// ---------------- legacy reduce + full-resim p2 (fallback tiers) ----------------
__global__ void dastar_reduce(const unsigned* __restrict__ sw, int* __restrict__ ctl,
                              int w0, int nw)
{
    if (ctl[1]) return;
    __shared__ unsigned aw[32];
    int tid = threadIdx.x;
    if (tid < nw) {
        unsigned a = 0xFFFFFFFFu;
        for (int b = 0; b < NB; ++b) a &= sw[b * 32 + w0 + tid];
        aw[tid] = a;
    }
    __syncthreads();
    if (tid == 0) {
        for (int w = 0; w < nw; ++w) {
            if (aw[w]) { ctl[0] = (w0 + w) * 32 + (__ffs(aw[w]) - 1); ctl[1] = 1; break; }
        }
    }
}

__global__ __launch_bounds__(64)
void dastar_p2full(const float* __restrict__ cm_g, const float* __restrict__ sm_g,
                   const float* __restrict__ gm_g, const int* __restrict__ ctl,
                   float* __restrict__ out)
{
    const int b   = blockIdx.x;
    const int tid = threadIdx.x;

    __shared__ __align__(16) float fe[HWC], gg[HWC], oo[HWC], hi[HWC], cmS[HWC], hhS[HWC], pp[HWC];
    __shared__ int goal_sh;

    const float4* cm4 = (const float4*)(cm_g + b * HWC);
    const float4* sm4 = (const float4*)(sm_g + b * HWC);
    const float4* gm4 = (const float4*)(gm_g + b * HWC);
    float cmr[16], oor[16];
#pragma unroll
    for (int q = 0; q < 4; ++q) {
        int i4 = tid * 4 + q;
        float4 c4 = cm4[i4];
        float4 s4 = sm4[i4];
        float4 g4 = gm4[i4];
        int base = i4 * 4;
        float cv[4] = {c4.x, c4.y, c4.z, c4.w};
        float sv[4] = {s4.x, s4.y, s4.z, s4.w};
        float gv[4] = {g4.x, g4.y, g4.z, g4.w};
#pragma unroll
        for (int j = 0; j < 4; ++j) {
            int i = base + j;
            cmr[q * 4 + j] = cv[j];
            oor[q * 4 + j] = sv[j];
            cmS[i] = cv[j];
            gg[i] = 0.0f; hi[i] = 0.0f; oo[i] = sv[j];
            if (gv[j] == 1.0f) goal_sh = i;
        }
    }
    __syncthreads();

    const int   goal = goal_sh;
    const float gy = (float)(goal >> 5), gx = (float)(goal & 31);
#pragma unroll
    for (int k = 0; k < 16; ++k) {
        int i = tid * 16 + k;
        float dy = (float)(i >> 5) - gy;
        float dx = (float)(i & 31) - gx;
        float h  = __fmul_rn(sqrtf(__fadd_rn(__fmul_rn(dy, dy), __fmul_rn(dx, dx))), cmr[k]);
        hhS[i] = h;
        fe[i]  = fe_expr(0.0f, h, oor[k]);
        pp[i]  = (float)goal;
    }
    __syncthreads();

    const int Tend = ctl[0];
    const int dyj = tid / 3 - 1, dxj = tid % 3 - 1;

    for (int t = 0; t <= Tend; ++t) {
        float bv; int bi;
        {
            float v[16];
            const float4* fe4 = (const float4*)fe;
#pragma unroll
            for (int q = 0; q < 4; ++q) {
                float4 x = fe4[tid * 4 + q];
                v[q * 4]     = x.x; v[q * 4 + 1] = x.y;
                v[q * 4 + 2] = x.z; v[q * 4 + 3] = x.w;
            }
            const int cbase = tid * 16;
            float v8[8]; int i8[8];
#pragma unroll
            for (int k = 0; k < 8; ++k) {
                bool tk = v[2 * k + 1] > v[2 * k];
                v8[k] = tk ? v[2 * k + 1] : v[2 * k];
                i8[k] = cbase + 2 * k + (tk ? 1 : 0);
            }
            float v4[4]; int i4a[4];
#pragma unroll
            for (int k = 0; k < 4; ++k) {
                bool tk = v8[2 * k + 1] > v8[2 * k];
                v4[k] = tk ? v8[2 * k + 1] : v8[2 * k];
                i4a[k] = tk ? i8[2 * k + 1] : i8[2 * k];
            }
            float v2[2]; int i2a[2];
#pragma unroll
            for (int k = 0; k < 2; ++k) {
                bool tk = v4[2 * k + 1] > v4[2 * k];
                v2[k] = tk ? v4[2 * k + 1] : v4[2 * k];
                i2a[k] = tk ? i4a[2 * k + 1] : i4a[2 * k];
            }
            bool tk = v2[1] > v2[0];
            bv = tk ? v2[1] : v2[0];
            bi = tk ? i2a[1] : i2a[0];
        }
#pragma unroll
        for (int m = 32; m >= 1; m >>= 1) {
            float ov = __shfl_xor(bv, m);
            int   oi = __shfl_xor(bi, m);
            combineMax(bv, bi, ov, oi);
        }
        const int  s      = bi;
        const bool solved = (s == goal);

        bool changed = false;
        if (tid < 9) {
            const int sy = s >> 5, sx = s & 31;
            if (tid == 4) {
                if (hi[s] != 1.0f) { hi[s] = 1.0f; changed = true; }
                if (!solved && oo[s] != 0.0f) { oo[s] = 0.0f; fe[s] = 0.0f; changed = true; }
            } else {
                int cy = sy + dyj, cx = sx + dxj;
                if (cy >= 0 && cy < GH && cx >= 0 && cx < GW) {
                    int   c  = (cy << 5) | cx;
                    float g2 = __fadd_rn(gg[s], (dyj != 0 && dxj != 0) ? 1.4142f : 1.0f);
                    float gc = gg[c], oc = oo[c], hc = hi[c], cmc = cmS[c];
                    float t1 = __fmul_rn(__fsub_rn(1.0f, oc), __fsub_rn(1.0f, hc));
                    float t2 = __fmul_rn(oc, (gc > g2) ? 1.0f : 0.0f);
                    float idxv = __fmul_rn(__fadd_rn(t1, t2), cmc);
                    if (idxv != 0.0f) {
                        changed = true;
                        float omi = __fsub_rn(1.0f, idxv);
                        float gn = __fadd_rn(__fmul_rn(g2, idxv), __fmul_rn(gc, omi));
                        float on = fminf(__fadd_rn(oc, idxv), 1.0f);
                        gg[c] = gn; oo[c] = on;
                        fe[c] = fe_expr(gn, hhS[c], on);
                        pp[c] = __fadd_rn(__fmul_rn((float)s, idxv), __fmul_rn(pp[c], omi));
                    }
                }
            }
        }
        unsigned long long chg = __ballot(changed);
        if (chg == 0ull) break;
        __syncthreads();
    }
    __syncthreads();

#pragma unroll
    for (int q = 0; q < 4; ++q) {
        int i4 = tid + (q << 6);
        ((float4*)(out + b * HWC))[i4] = ((const float4*)hi)[i4];
    }
#pragma unroll
    for (int q = 0; q < 4; ++q)
        ((float4*)fe)[tid + (q << 6)] = make_float4(0.f, 0.f, 0.f, 0.f);
    __syncthreads();
    if (tid == 0) {
        fe[goal] = 1.0f;
        int loc = (int)pp[goal];
        for (int i2 = 0; i2 < Tend; ++i2) {
            int w = (loc < 0) ? loc + HWC : loc;
            if (w >= 0 && w < HWC) {
                if (fe[w] == 1.0f) break;
                fe[w] = 1.0f;
            }
            int gidx = w < 0 ? 0 : (w > HWC - 1 ? HWC - 1 : w);
            loc = (int)pp[gidx];
        }
    }
    __syncthreads();
#pragma unroll
    for (int q = 0; q < 4; ++q) {
        int i4 = tid + (q << 6);
        ((float4*)(out + NB * HWC + b * HWC))[i4] = ((const float4*)fe)[i4];
    }
}

extern "C" void kernel_launch(void* const* d_in, const int* in_sizes, int n_in,
                              void* d_out, int out_size, void* d_ws, size_t ws_size,
                              hipStream_t stream)
{
    const float* cm = (const float*)d_in[0];
    const float* sm = (const float*)d_in[1];
    const float* gm = (const float*)d_in[2];
    float* out = (float*)d_out;

    unsigned* sw    = (unsigned*)d_ws;
    int*      ctl   = (int*)((char*)d_ws + WS_CTL);
    int*      stat  = (int*)((char*)d_ws + WS_STAT);
    int*      lgend = (int*)((char*)d_ws + WS_LOGEND);
    float*    state = (float*)((char*)d_ws + WS_STATE);
    unsigned* logg  = (unsigned*)((char*)d_ws + WS_LOG);

    if (ws_size >= WS_NEED_FAST) {
        for (int k = 0; k < NCH; ++k)
            dastar_p1<1><<<dim3(NB), dim3(64), 0, stream>>>(cm, sm, gm, sw, ctl, state, stat,
                                                            logg, lgend, k * CH, CH);
        dastar_p2her<<<dim3(NB), dim3(64), 0, stream>>>(gm, sw, ctl, logg, lgend, out);
    } else if (ws_size >= WS_NEED_R3) {
        for (int k = 0; k < NCH; ++k) {
            dastar_p1<0><<<dim3(NB), dim3(64), 0, stream>>>(cm, sm, gm, sw, ctl, state, stat,
                                                            (unsigned*)nullptr, (int*)nullptr, k * CH, CH);
            dastar_reduce<<<dim3(1), dim3(64), 0, stream>>>(sw, ctl, k * (CH / 32), CH / 32);
        }
        dastar_p2full<<<dim3(NB), dim3(64), 0, stream>>>(cm, sm, gm, ctl, out);
    } else {
        dastar_p1<0><<<dim3(NB), dim3(64), 0, stream>>>(cm, sm, gm, sw, ctl, state, stat,
                                                        (unsigned*)nullptr, (int*)nullptr, 0, HWC);
        dastar_reduce<<<dim3(1), dim3(64), 0, stream>>>(sw, ctl, 0, 32);
        dastar_p2full<<<dim3(NB), dim3(64), 0, stream>>>(cm, sm, gm, ctl, out);
    }
}

// Round 5
// 152.087 us; speedup vs baseline: 10.2984x; 1.3043x over previous
//
#include <hip/hip_runtime.h>
#include <math.h>

#define HWC 1024      // H*W
#define NB  32        // batch
#define GH  32
#define GW  32
#define WSTEP 32      // steps per sync window
#define NWIN (HWC / WSTEP)

// d_ws layout (bytes)
#define WS_BAR   0                          // unsigned bar[NWIN] (zeroed each call by init kernel)
#define WS_SWIN  256                        // unsigned swin[NWIN][NB] window solved-bit words
#define WS_STW   (WS_SWIN + NWIN * NB * 4)  // unsigned stw[NWIN][NB] status words

__device__ __forceinline__ float fe_expr(float g, float h, float o) {
    // EXACT reference chain: exp(-(g+h)*inv_c) * open, inv_c = 1/32 (exact scale)
    return __fmul_rn(expf(__fmul_rn(__fadd_rn(g, h), -0.03125f)), o);
}

// DPP helpers: old = src, bound_ctrl = false -> invalid-source lanes keep own value
// (identity for max/and), so no 0-fill semantics to worry about.
template<int CTRL>
__device__ __forceinline__ float dppmax(float m) {
    int sh = __builtin_amdgcn_update_dpp(__float_as_int(m), __float_as_int(m), CTRL, 0xF, 0xF, false);
    return fmaxf(m, __int_as_float(sh));
}
template<int CTRL>
__device__ __forceinline__ unsigned dppand(unsigned m) {
    int sh = __builtin_amdgcn_update_dpp((int)m, (int)m, CTRL, 0xF, 0xF, false);
    return m & (unsigned)sh;
}

__global__ void dastar_init(unsigned* __restrict__ bar) {
    if (threadIdx.x < NWIN) bar[threadIdx.x] = 0u;
}

// One persistent block per batch; 64 threads (1 wave). All state + step log in LDS.
// Window barrier via device-scope atomics in d_ws (32 blocks are always co-resident).
__global__ __launch_bounds__(64)
void dastar_fused(const float* __restrict__ cm_g, const float* __restrict__ sm_g,
                  const float* __restrict__ gm_g, unsigned* __restrict__ swin,
                  unsigned* __restrict__ stw, unsigned* __restrict__ bar,
                  float* __restrict__ out)
{
    const int b   = blockIdx.x;
    const int tid = threadIdx.x;   // 0..63

    __shared__ __align__(16) float fe[HWC], gg[HWC], oo[HWC], hi[HWC], cmS[HWC], hhS[HWC];
    __shared__ unsigned slog[HWC * 9];   // per-step: cols 0..8 (col4 = s, others = idxv bits)
    __shared__ int goal_sh;

    // ---- init: thread owns cells 16*tid..16*tid+15 ----
    const float4* cm4 = (const float4*)(cm_g + b * HWC);
    const float4* sm4 = (const float4*)(sm_g + b * HWC);
    const float4* gm4 = (const float4*)(gm_g + b * HWC);
    float cmr[16], oor[16];
#pragma unroll
    for (int q = 0; q < 4; ++q) {
        int i4 = tid * 4 + q;
        float4 c4 = cm4[i4];
        float4 s4 = sm4[i4];
        float4 g4 = gm4[i4];
        int base = i4 * 4;
        float cv[4] = {c4.x, c4.y, c4.z, c4.w};
        float sv[4] = {s4.x, s4.y, s4.z, s4.w};
        float gv[4] = {g4.x, g4.y, g4.z, g4.w};
#pragma unroll
        for (int j = 0; j < 4; ++j) {
            int i = base + j;
            cmr[q * 4 + j] = cv[j];
            oor[q * 4 + j] = sv[j];
            cmS[i] = cv[j];
            gg[i] = 0.0f; hi[i] = 0.0f; oo[i] = sv[j];
            if (gv[j] == 1.0f) goal_sh = i;   // unique goal
        }
    }
    __syncthreads();

    const int   goal = goal_sh;
    const float gy = (float)(goal >> 5), gx = (float)(goal & 31);
#pragma unroll
    for (int k = 0; k < 16; ++k) {
        int i = tid * 16 + k;
        float dy = (float)(i >> 5) - gy;
        float dx = (float)(i & 31) - gx;
        float h  = __fmul_rn(sqrtf(__fadd_rn(__fmul_rn(dy, dy), __fmul_rn(dx, dx))), cmr[k]);
        hhS[i] = h;
        fe[i]  = fe_expr(0.0f, h, oor[k]);
    }
    __syncthreads();

    const int dyj = tid / 3 - 1, dxj = tid % 3 - 1;
    bool frozen = false, fsolved = false;
    int  fstep = 0;
    int  tstar = HWC - 1;

    for (int win = 0; win < NWIN; ++win) {
        unsigned word;
        if (!frozen) {
            word = 0u;
            const int tbeg = win * WSTEP;
            for (int t = tbeg; t < tbeg + WSTEP; ++t) {
                // ---- scan: 4x ds_read_b128, local first-index argmax tree ----
                float v[16];
                const float4* fe4 = (const float4*)fe;
#pragma unroll
                for (int q = 0; q < 4; ++q) {
                    float4 x = fe4[tid * 4 + q];
                    v[q * 4]     = x.x; v[q * 4 + 1] = x.y;
                    v[q * 4 + 2] = x.z; v[q * 4 + 3] = x.w;
                }
                const int cbase = tid * 16;
                float v8[8]; int i8[8];
#pragma unroll
                for (int k = 0; k < 8; ++k) {
                    bool tk = v[2 * k + 1] > v[2 * k];
                    v8[k] = tk ? v[2 * k + 1] : v[2 * k];
                    i8[k] = cbase + 2 * k + (tk ? 1 : 0);
                }
                float v4[4]; int i4a[4];
#pragma unroll
                for (int k = 0; k < 4; ++k) {
                    bool tk = v8[2 * k + 1] > v8[2 * k];
                    v4[k] = tk ? v8[2 * k + 1] : v8[2 * k];
                    i4a[k] = tk ? i8[2 * k + 1] : i8[2 * k];
                }
                float v2[2]; int i2a[2];
#pragma unroll
                for (int k = 0; k < 2; ++k) {
                    bool tk = v4[2 * k + 1] > v4[2 * k];
                    v2[k] = tk ? v4[2 * k + 1] : v4[2 * k];
                    i2a[k] = tk ? i4a[2 * k + 1] : i4a[2 * k];
                }
                bool tk0 = v2[1] > v2[0];
                float bv = tk0 ? v2[1] : v2[0];
                int   bi = tk0 ? i2a[1] : i2a[0];

                // ---- global argmax: DPP value max -> uniform; ballot for first lane ----
                float m = bv;
                m = dppmax<0x111>(m);   // row_shr:1
                m = dppmax<0x112>(m);   // row_shr:2
                m = dppmax<0x114>(m);   // row_shr:4
                m = dppmax<0x118>(m);   // row_shr:8
                m = dppmax<0x142>(m);   // row_bcast:15
                m = dppmax<0x143>(m);   // row_bcast:31
                float gmax = __int_as_float(__builtin_amdgcn_readlane(__float_as_int(m), 63));
                unsigned long long bl = __ballot(bv == gmax);
                int lsel = (int)__ffsll(bl) - 1;
                if (lsel < 0) lsel = 0;                     // insurance (bl!=0 by construction)
                const int  s      = __builtin_amdgcn_readlane(bi, lsel);
                const bool solved = (s == goal);

                // ---- update: 8 neighbors + center (exact reference blend chain) ----
                bool changed = false;
                float lidx = 0.0f;
                if (tid < 9) {
                    const int sy = s >> 5, sx = s & 31;
                    if (tid == 4) {
                        if (hi[s] != 1.0f) { hi[s] = 1.0f; changed = true; }
                        if (!solved && oo[s] != 0.0f) { oo[s] = 0.0f; fe[s] = 0.0f; changed = true; }
                    } else {
                        int cy = sy + dyj, cx = sx + dxj;
                        if (cy >= 0 && cy < GH && cx >= 0 && cx < GW) {
                            int   c  = (cy << 5) | cx;
                            float g2 = __fadd_rn(gg[s], (dyj != 0 && dxj != 0) ? 1.4142f : 1.0f);
                            float gc = gg[c], oc = oo[c], hc = hi[c], cmc = cmS[c];
                            float t1 = __fmul_rn(__fsub_rn(1.0f, oc), __fsub_rn(1.0f, hc));
                            float t2 = __fmul_rn(oc, (gc > g2) ? 1.0f : 0.0f);
                            float idxv = __fmul_rn(__fadd_rn(t1, t2), cmc);
                            lidx = idxv;
                            if (idxv != 0.0f) {
                                changed = true;
                                float omi = __fsub_rn(1.0f, idxv);
                                float gn = __fadd_rn(__fmul_rn(g2, idxv), __fmul_rn(gc, omi));
                                float on = fminf(__fadd_rn(oc, idxv), 1.0f);
                                gg[c] = gn; oo[c] = on;
                                fe[c] = fe_expr(gn, hhS[c], on);
                            }
                        }
                    }
                    slog[t * 9 + tid] = (tid == 4) ? (unsigned)s : __float_as_uint(lidx);
                }
                unsigned long long chg = __ballot(changed);

                if (solved) word |= (1u << (t & 31));
                if (chg == 0ull) {   // fixed point: identical selection forever
                    if (solved) word |= ~((1u << (t & 31)) - 1u);
                    frozen = true; fsolved = solved; fstep = t;
                    break;
                }
                __syncthreads();
            }
        } else {
            word = fsolved ? 0xFFFFFFFFu : 0u;
        }

        // ---- publish window word + status, device barrier ----
        if (tid == 0) {
            __hip_atomic_store(&swin[win * NB + b], word, __ATOMIC_RELEASE, __HIP_MEMORY_SCOPE_AGENT);
            __hip_atomic_store(&stw[win * NB + b], frozen ? (fsolved ? 1u : 2u) : 0u,
                               __ATOMIC_RELEASE, __HIP_MEMORY_SCOPE_AGENT);
            __hip_atomic_fetch_add(&bar[win], 1u, __ATOMIC_ACQ_REL, __HIP_MEMORY_SCOPE_AGENT);
            unsigned guard = 0u;
            while (__hip_atomic_load(&bar[win], __ATOMIC_ACQUIRE, __HIP_MEMORY_SCOPE_AGENT) < NB) {
                __builtin_amdgcn_s_sleep(8);
                if (++guard > 4000000u) break;   // watchdog (never hit in practice)
            }
        }
        __syncthreads();

        // ---- redundant reduce (every block computes the same decision) ----
        unsigned wv = __hip_atomic_load(&swin[win * NB + (tid & 31)], __ATOMIC_ACQUIRE, __HIP_MEMORY_SCOPE_AGENT);
        unsigned sv = __hip_atomic_load(&stw[win * NB + (tid & 31)], __ATOMIC_ACQUIRE, __HIP_MEMORY_SCOPE_AGENT);
        unsigned A = wv;
        A = dppand<0x111>(A); A = dppand<0x112>(A); A = dppand<0x114>(A);
        A = dppand<0x118>(A); A = dppand<0x142>(A); A = dppand<0x143>(A);
        A = (unsigned)__builtin_amdgcn_readlane((int)A, 63);
        bool allfroz = (__ballot(sv != 0u) == 0xFFFFFFFFFFFFFFFFull);
        if (A) { tstar = win * WSTEP + (__ffs(A) - 1); break; }
        if (allfroz) break;   // no batch will ever change again -> never all-solved -> tstar = 1023
    }
    __syncthreads();

    // ================= epilogue (per block, all from LDS) =================
    const int Tl = frozen ? min(tstar, fstep) : tstar;

    // hist = union of selected cells for t <= Tl (rebuild; live hi may overshoot tstar)
#pragma unroll
    for (int q = 0; q < 4; ++q)
        ((float4*)hi)[tid + (q << 6)] = make_float4(0.f, 0.f, 0.f, 0.f);
    __syncthreads();
    for (int t = tid; t <= Tl; t += 64) hi[(int)slog[t * 9 + 4]] = 1.0f;
    __syncthreads();
#pragma unroll
    for (int q = 0; q < 4; ++q) {
        int i4 = tid + (q << 6);
        ((float4*)(out + b * HWC))[i4] = ((const float4*)hi)[i4];
    }

    // parents replay into cmS (reused as pp); path buffer = hhS (reused as pb)
    const float goalf = (float)goal;
#pragma unroll
    for (int k = 0; k < 16; ++k) {
        int i = tid * 16 + k;
        cmS[i] = goalf;    // pp
        hhS[i] = 0.0f;     // pb
    }
    __syncthreads();
    if (tid < 9 && tid != 4) {
        for (int t = 0; t <= Tl; ++t) {
            float idxv = __uint_as_float(slog[t * 9 + tid]);
            if (idxv != 0.0f) {
                int   su = (int)slog[t * 9 + 4];
                int   c  = su + (dyj << 5) + dxj;    // idxv!=0 implies in-bounds
                float omi = __fsub_rn(1.0f, idxv);
                cmS[c] = __fadd_rn(__fmul_rn((float)su, idxv), __fmul_rn(cmS[c], omi));
            }
        }
    }
    __syncthreads();

    // backtrack: tstar iterations, JAX index semantics, revisit break
    if (tid == 0) {
        hhS[goal] = 1.0f;
        int loc = (int)cmS[goal];
        for (int i2 = 0; i2 < tstar; ++i2) {
            int w = (loc < 0) ? loc + HWC : loc;              // JAX wraps negatives once
            if (w >= 0 && w < HWC) {
                if (hhS[w] == 1.0f) break;                    // revisit: chase cycles, no new cells
                hhS[w] = 1.0f;
            }
            int gidx = w < 0 ? 0 : (w > HWC - 1 ? HWC - 1 : w);
            loc = (int)cmS[gidx];
        }
    }
    __syncthreads();
#pragma unroll
    for (int q = 0; q < 4; ++q) {
        int i4 = tid + (q << 6);
        ((float4*)(out + NB * HWC + b * HWC))[i4] = ((const float4*)hhS)[i4];
    }
}

extern "C" void kernel_launch(void* const* d_in, const int* in_sizes, int n_in,
                              void* d_out, int out_size, void* d_ws, size_t ws_size,
                              hipStream_t stream)
{
    const float* cm = (const float*)d_in[0];
    const float* sm = (const float*)d_in[1];
    const float* gm = (const float*)d_in[2];
    float* out = (float*)d_out;

    unsigned* bar  = (unsigned*)((char*)d_ws + WS_BAR);
    unsigned* swin = (unsigned*)((char*)d_ws + WS_SWIN);
    unsigned* stw  = (unsigned*)((char*)d_ws + WS_STW);

    dastar_init<<<1, 64, 0, stream>>>(bar);
    dastar_fused<<<dim3(NB), dim3(64), 0, stream>>>(cm, sm, gm, swin, stw, bar, out);
}

// Round 6
// 144.223 us; speedup vs baseline: 10.8599x; 1.0545x over previous
//
#include <hip/hip_runtime.h>
#include <math.h>

#define HWC 1024      // H*W
#define NB  32        // batch
#define GH  32
#define GW  32
#define WSTEP 32      // steps per sync window
#define NWIN (HWC / WSTEP)

// d_ws layout (bytes)
#define WS_BAR   0                          // unsigned bar[NWIN] (zeroed each call by init kernel)
#define WS_SWIN  256                        // unsigned swin[NWIN][NB] window solved-bit words
#define WS_STW   (WS_SWIN + NWIN * NB * 4)  // unsigned stw[NWIN][NB] status words

// transposed fe storage: cell i -> phys word (i&15)*64 + (i>>4)
// scan (lane L reads feT[k*64+L]) hits bank L%32 -> 2 lanes/bank = conflict-free
#define FEIDX(i) ((((i) & 15) << 6) | ((i) >> 4))

__device__ __forceinline__ float fe_expr(float g, float h, float o) {
    // EXACT reference chain: exp(-(g+h)*inv_c) * open, inv_c = 1/32 (exact scale)
    return __fmul_rn(expf(__fmul_rn(__fadd_rn(g, h), -0.03125f)), o);
}

// DPP helpers: old = src, bound_ctrl = false -> invalid-source lanes keep own value
template<int CTRL>
__device__ __forceinline__ float dppmax(float m) {
    int sh = __builtin_amdgcn_update_dpp(__float_as_int(m), __float_as_int(m), CTRL, 0xF, 0xF, false);
    return fmaxf(m, __int_as_float(sh));
}
template<int CTRL>
__device__ __forceinline__ unsigned dppand(unsigned m) {
    int sh = __builtin_amdgcn_update_dpp((int)m, (int)m, CTRL, 0xF, 0xF, false);
    return m & (unsigned)sh;
}

__global__ void dastar_init(unsigned* __restrict__ bar) {
    if (threadIdx.x < NWIN) bar[threadIdx.x] = 0u;
}

// One persistent block per batch; 64 threads (1 wave). All state + step log in LDS.
// Single-wave workgroup: NO __syncthreads in the step loop (program order + lgkmcnt
// hazard tracking orders all LDS ops for one wave).
__global__ __launch_bounds__(64)
void dastar_fused(const float* __restrict__ cm_g, const float* __restrict__ sm_g,
                  const float* __restrict__ gm_g, unsigned* __restrict__ swin,
                  unsigned* __restrict__ stw, unsigned* __restrict__ bar,
                  float* __restrict__ out)
{
    const int b   = blockIdx.x;
    const int tid = threadIdx.x;   // 0..63

    __shared__ __align__(16) float feT[HWC];   // transposed (FEIDX)
    __shared__ __align__(16) float gg[HWC], oo[HWC], hi[HWC], cmS[HWC], hhS[HWC];
    __shared__ unsigned slog[HWC * 9];   // per-step: col4 = s, others = idxv bits
    __shared__ int goal_sh;

    // ---- init: thread owns cells 16*tid..16*tid+15 ----
    const float4* cm4 = (const float4*)(cm_g + b * HWC);
    const float4* sm4 = (const float4*)(sm_g + b * HWC);
    const float4* gm4 = (const float4*)(gm_g + b * HWC);
    float cmr[16], oor[16];
#pragma unroll
    for (int q = 0; q < 4; ++q) {
        int i4 = tid * 4 + q;
        float4 c4 = cm4[i4];
        float4 s4 = sm4[i4];
        float4 g4 = gm4[i4];
        int base = i4 * 4;
        float cv[4] = {c4.x, c4.y, c4.z, c4.w};
        float sv[4] = {s4.x, s4.y, s4.z, s4.w};
        float gv[4] = {g4.x, g4.y, g4.z, g4.w};
#pragma unroll
        for (int j = 0; j < 4; ++j) {
            int i = base + j;
            cmr[q * 4 + j] = cv[j];
            oor[q * 4 + j] = sv[j];
            cmS[i] = cv[j];
            gg[i] = 0.0f; hi[i] = 0.0f; oo[i] = sv[j];
            if (gv[j] == 1.0f) goal_sh = i;   // unique goal
        }
    }
    __syncthreads();

    const int   goal = goal_sh;
    const float gy = (float)(goal >> 5), gx = (float)(goal & 31);
#pragma unroll
    for (int k = 0; k < 16; ++k) {
        int i = tid * 16 + k;
        float dy = (float)(i >> 5) - gy;
        float dx = (float)(i & 31) - gx;
        float h  = __fmul_rn(sqrtf(__fadd_rn(__fmul_rn(dy, dy), __fmul_rn(dx, dx))), cmr[k]);
        hhS[i] = h;
        feT[(k << 6) + tid] = fe_expr(0.0f, h, oor[k]);   // phys = k*64 + tid, conflict-free
    }
    __syncthreads();

    const int dyj = tid / 3 - 1, dxj = tid % 3 - 1;
    bool frozen = false, fsolved = false;
    int  fstep = 0;
    int  tstar = HWC - 1;

    for (int win = 0; win < NWIN; ++win) {
        unsigned word;
        if (!frozen) {
            word = 0u;
            const int tbeg = win * WSTEP;
            for (int t = tbeg; t < tbeg + WSTEP; ++t) {
                // ---- scan: 16 strided ds_read_b32 (one base, imm offsets), bank-conflict-free ----
                float v[16];
#pragma unroll
                for (int k = 0; k < 16; ++k) v[k] = feT[(k << 6) + tid];

                const int cbase = tid * 16;
                float v8[8]; int i8[8];
#pragma unroll
                for (int k = 0; k < 8; ++k) {
                    bool tk = v[2 * k + 1] > v[2 * k];
                    v8[k] = tk ? v[2 * k + 1] : v[2 * k];
                    i8[k] = cbase + 2 * k + (tk ? 1 : 0);
                }
                float v4[4]; int i4a[4];
#pragma unroll
                for (int k = 0; k < 4; ++k) {
                    bool tk = v8[2 * k + 1] > v8[2 * k];
                    v4[k] = tk ? v8[2 * k + 1] : v8[2 * k];
                    i4a[k] = tk ? i8[2 * k + 1] : i8[2 * k];
                }
                float v2[2]; int i2a[2];
#pragma unroll
                for (int k = 0; k < 2; ++k) {
                    bool tk = v4[2 * k + 1] > v4[2 * k];
                    v2[k] = tk ? v4[2 * k + 1] : v4[2 * k];
                    i2a[k] = tk ? i4a[2 * k + 1] : i4a[2 * k];
                }
                bool tk0 = v2[1] > v2[0];
                float bv = tk0 ? v2[1] : v2[0];
                int   bi = tk0 ? i2a[1] : i2a[0];

                // ---- global argmax: DPP value max -> uniform; ballot for first lane ----
                // lane-major blocked ownership => lowest lane == smallest cell index
                float m = bv;
                m = dppmax<0x111>(m);   // row_shr:1
                m = dppmax<0x112>(m);   // row_shr:2
                m = dppmax<0x114>(m);   // row_shr:4
                m = dppmax<0x118>(m);   // row_shr:8
                m = dppmax<0x142>(m);   // row_bcast:15
                m = dppmax<0x143>(m);   // row_bcast:31
                float gmax = __int_as_float(__builtin_amdgcn_readlane(__float_as_int(m), 63));
                unsigned long long bl = __ballot(bv == gmax);
                int lsel = (int)__ffsll(bl) - 1;
                if (lsel < 0) lsel = 0;                     // insurance (bl!=0 by construction)
                const int  s      = __builtin_amdgcn_readlane(bi, lsel);
                const bool solved = (s == goal);

                // ---- update: 8 neighbors + center (exact reference blend chain) ----
                bool changed = false;
                float lidx = 0.0f;
                if (tid < 9) {
                    const int sy = s >> 5, sx = s & 31;
                    if (tid == 4) {
                        if (hi[s] != 1.0f) { hi[s] = 1.0f; changed = true; }
                        if (!solved && oo[s] != 0.0f) { oo[s] = 0.0f; feT[FEIDX(s)] = 0.0f; changed = true; }
                    } else {
                        int cy = sy + dyj, cx = sx + dxj;
                        if (cy >= 0 && cy < GH && cx >= 0 && cx < GW) {
                            int   c  = (cy << 5) | cx;
                            float g2 = __fadd_rn(gg[s], (dyj != 0 && dxj != 0) ? 1.4142f : 1.0f);
                            float gc = gg[c], oc = oo[c], hc = hi[c], cmc = cmS[c];
                            float t1 = __fmul_rn(__fsub_rn(1.0f, oc), __fsub_rn(1.0f, hc));
                            float t2 = __fmul_rn(oc, (gc > g2) ? 1.0f : 0.0f);
                            float idxv = __fmul_rn(__fadd_rn(t1, t2), cmc);
                            lidx = idxv;
                            if (idxv != 0.0f) {
                                changed = true;
                                float omi = __fsub_rn(1.0f, idxv);
                                float gn = __fadd_rn(__fmul_rn(g2, idxv), __fmul_rn(gc, omi));
                                float on = fminf(__fadd_rn(oc, idxv), 1.0f);
                                gg[c] = gn; oo[c] = on;
                                feT[FEIDX(c)] = fe_expr(gn, hhS[c], on);
                            }
                        }
                    }
                    slog[t * 9 + tid] = (tid == 4) ? (unsigned)s : __float_as_uint(lidx);
                }
                unsigned long long chg = __ballot(changed);

                if (solved) word |= (1u << (t & 31));
                if (chg == 0ull) {   // fixed point: identical selection forever
                    if (solved) word |= ~((1u << (t & 31)) - 1u);
                    frozen = true; fsolved = solved; fstep = t;
                    break;
                }
                // no __syncthreads: single wave, in-order LDS + compiler lgkmcnt hazards
            }
        } else {
            word = fsolved ? 0xFFFFFFFFu : 0u;
        }

        // ---- publish window word + status, device barrier (all-lane spin) ----
        if (tid == 0) {
            __hip_atomic_store(&swin[win * NB + b], word, __ATOMIC_RELEASE, __HIP_MEMORY_SCOPE_AGENT);
            __hip_atomic_store(&stw[win * NB + b], frozen ? (fsolved ? 1u : 2u) : 0u,
                               __ATOMIC_RELEASE, __HIP_MEMORY_SCOPE_AGENT);
            __hip_atomic_fetch_add(&bar[win], 1u, __ATOMIC_ACQ_REL, __HIP_MEMORY_SCOPE_AGENT);
        }
        {
            unsigned guard = 0u;
            while (__hip_atomic_load(&bar[win], __ATOMIC_ACQUIRE, __HIP_MEMORY_SCOPE_AGENT) < NB) {
                __builtin_amdgcn_s_sleep(8);
                if (++guard > 4000000u) break;   // watchdog (never hit in practice)
            }
        }

        // ---- redundant reduce (every block computes the same decision) ----
        unsigned wv = __hip_atomic_load(&swin[win * NB + (tid & 31)], __ATOMIC_ACQUIRE, __HIP_MEMORY_SCOPE_AGENT);
        unsigned sv = __hip_atomic_load(&stw[win * NB + (tid & 31)], __ATOMIC_ACQUIRE, __HIP_MEMORY_SCOPE_AGENT);
        unsigned A = wv;
        A = dppand<0x111>(A); A = dppand<0x112>(A); A = dppand<0x114>(A);
        A = dppand<0x118>(A); A = dppand<0x142>(A); A = dppand<0x143>(A);
        A = (unsigned)__builtin_amdgcn_readlane((int)A, 63);
        bool allfroz = (__ballot(sv != 0u) == 0xFFFFFFFFFFFFFFFFull);
        if (A) { tstar = win * WSTEP + (__ffs(A) - 1); break; }
        if (allfroz) break;   // no batch will ever change -> never all-solved -> tstar = 1023
    }
    __syncthreads();

    // ================= epilogue (per block, all from LDS) =================
    const int Tl = frozen ? min(tstar, fstep) : tstar;

    // hist = union of selected cells for t <= Tl (rebuild; live hi may overshoot tstar)
#pragma unroll
    for (int q = 0; q < 4; ++q)
        ((float4*)hi)[tid + (q << 6)] = make_float4(0.f, 0.f, 0.f, 0.f);
    __syncthreads();
    for (int t = tid; t <= Tl; t += 64) hi[(int)slog[t * 9 + 4]] = 1.0f;
    __syncthreads();
#pragma unroll
    for (int q = 0; q < 4; ++q) {
        int i4 = tid + (q << 6);
        ((float4*)(out + b * HWC))[i4] = ((const float4*)hi)[i4];
    }

    // parents replay into cmS (reused as pp); path buffer = hhS (reused as pb)
    const float goalf = (float)goal;
#pragma unroll
    for (int k = 0; k < 16; ++k) {
        int i = tid * 16 + k;
        cmS[i] = goalf;    // pp
        hhS[i] = 0.0f;     // pb
    }
    __syncthreads();
    if (tid < 9 && tid != 4) {
        for (int t = 0; t <= Tl; ++t) {
            float idxv = __uint_as_float(slog[t * 9 + tid]);
            if (idxv != 0.0f) {
                int   su = (int)slog[t * 9 + 4];
                int   c  = su + (dyj << 5) + dxj;    // idxv!=0 implies in-bounds
                float omi = __fsub_rn(1.0f, idxv);
                cmS[c] = __fadd_rn(__fmul_rn((float)su, idxv), __fmul_rn(cmS[c], omi));
            }
        }
    }
    __syncthreads();

    // backtrack: tstar iterations, JAX index semantics, revisit break
    if (tid == 0) {
        hhS[goal] = 1.0f;
        int loc = (int)cmS[goal];
        for (int i2 = 0; i2 < tstar; ++i2) {
            int w = (loc < 0) ? loc + HWC : loc;              // JAX wraps negatives once
            if (w >= 0 && w < HWC) {
                if (hhS[w] == 1.0f) break;                    // revisit: chase cycles, no new cells
                hhS[w] = 1.0f;
            }
            int gidx = w < 0 ? 0 : (w > HWC - 1 ? HWC - 1 : w);
            loc = (int)cmS[gidx];
        }
    }
    __syncthreads();
#pragma unroll
    for (int q = 0; q < 4; ++q) {
        int i4 = tid + (q << 6);
        ((float4*)(out + NB * HWC + b * HWC))[i4] = ((const float4*)hhS)[i4];
    }
}

extern "C" void kernel_launch(void* const* d_in, const int* in_sizes, int n_in,
                              void* d_out, int out_size, void* d_ws, size_t ws_size,
                              hipStream_t stream)
{
    const float* cm = (const float*)d_in[0];
    const float* sm = (const float*)d_in[1];
    const float* gm = (const float*)d_in[2];
    float* out = (float*)d_out;

    unsigned* bar  = (unsigned*)((char*)d_ws + WS_BAR);
    unsigned* swin = (unsigned*)((char*)d_ws + WS_SWIN);
    unsigned* stw  = (unsigned*)((char*)d_ws + WS_STW);

    dastar_init<<<1, 64, 0, stream>>>(bar);
    dastar_fused<<<dim3(NB), dim3(64), 0, stream>>>(cm, sm, gm, swin, stw, bar, out);
}

// Round 7
// 132.591 us; speedup vs baseline: 11.8126x; 1.0877x over previous
//
#include <hip/hip_runtime.h>
#include <math.h>

#define HWC 1024      // H*W
#define NB  32        // batch
#define GH  32
#define GW  32
#define NWORD 32      // 32-step words
#define NPHASE 30     // phase p reduces words [0,3+p)

// d_ws layout (bytes)
#define WS_BAR   0                          // unsigned bar[32] (zeroed each call by init kernel)
#define WS_SWIN  256                        // unsigned swin[NWORD][NB] solved-bit words
#define WS_STW   (WS_SWIN + NWORD * NB * 4) // unsigned stw[NPHASE][NB] status words

// transposed fe storage: cell i -> phys word (i&15)*64 + (i>>4)
// scan (lane L reads feT[k*64+L]) hits bank L%32 -> 2 lanes/bank = conflict-free
#define FEIDX(i) ((((i) & 15) << 6) | ((i) >> 4))

__device__ __forceinline__ float fe_expr(float g, float h, float o) {
    // EXACT reference chain: exp(-(g+h)*inv_c) * open, inv_c = 1/32 (exact scale)
    return __fmul_rn(expf(__fmul_rn(__fadd_rn(g, h), -0.03125f)), o);
}

// DPP helpers: old = src, bound_ctrl = false -> invalid-source lanes keep own value
template<int CTRL>
__device__ __forceinline__ float dppmax(float m) {
    int sh = __builtin_amdgcn_update_dpp(__float_as_int(m), __float_as_int(m), CTRL, 0xF, 0xF, false);
    return fmaxf(m, __int_as_float(sh));
}
template<int CTRL>
__device__ __forceinline__ unsigned dppand(unsigned m) {
    int sh = __builtin_amdgcn_update_dpp((int)m, (int)m, CTRL, 0xF, 0xF, false);
    return m & (unsigned)sh;
}

__global__ void dastar_init(unsigned* __restrict__ bar) {
    if (threadIdx.x < 32) bar[threadIdx.x] = 0u;
}

// One persistent block per batch; 64 threads (1 wave). All state + step log in LDS.
// Single-wave workgroup: no __syncthreads in the step loop.
__global__ __launch_bounds__(64)
void dastar_fused(const float* __restrict__ cm_g, const float* __restrict__ sm_g,
                  const float* __restrict__ gm_g, unsigned* __restrict__ swin,
                  unsigned* __restrict__ stw, unsigned* __restrict__ bar,
                  float* __restrict__ out)
{
    const int b   = blockIdx.x;
    const int tid = threadIdx.x;   // 0..63

    __shared__ __align__(16) float feT[HWC];   // transposed (FEIDX)
    __shared__ __align__(16) float gg[HWC], oo[HWC], hi[HWC], cmS[HWC], hhS[HWC];
    __shared__ unsigned slog[HWC * 9];   // per-step: col4 = s, others = idxv bits
    __shared__ int goal_sh;

    // ---- init: thread owns cells 16*tid..16*tid+15 ----
    const float4* cm4 = (const float4*)(cm_g + b * HWC);
    const float4* sm4 = (const float4*)(sm_g + b * HWC);
    const float4* gm4 = (const float4*)(gm_g + b * HWC);
    float cmr[16], oor[16];
#pragma unroll
    for (int q = 0; q < 4; ++q) {
        int i4 = tid * 4 + q;
        float4 c4 = cm4[i4];
        float4 s4 = sm4[i4];
        float4 g4 = gm4[i4];
        int base = i4 * 4;
        float cv[4] = {c4.x, c4.y, c4.z, c4.w};
        float sv[4] = {s4.x, s4.y, s4.z, s4.w};
        float gv[4] = {g4.x, g4.y, g4.z, g4.w};
#pragma unroll
        for (int j = 0; j < 4; ++j) {
            int i = base + j;
            cmr[q * 4 + j] = cv[j];
            oor[q * 4 + j] = sv[j];
            cmS[i] = cv[j];
            gg[i] = 0.0f; hi[i] = 0.0f; oo[i] = sv[j];
            if (gv[j] == 1.0f) goal_sh = i;   // unique goal
        }
    }
    __syncthreads();

    const int   goal = goal_sh;
    const float gy = (float)(goal >> 5), gx = (float)(goal & 31);
#pragma unroll
    for (int k = 0; k < 16; ++k) {
        int i = tid * 16 + k;
        float dy = (float)(i >> 5) - gy;
        float dx = (float)(i & 31) - gx;
        float h  = __fmul_rn(sqrtf(__fadd_rn(__fmul_rn(dy, dy), __fmul_rn(dx, dx))), cmr[k]);
        hhS[i] = h;
        feT[(k << 6) + tid] = fe_expr(0.0f, h, oor[k]);   // phys = k*64 + tid, conflict-free
    }
    __syncthreads();

    const int dyj = tid / 3 - 1, dxj = tid % 3 - 1;
    bool frozen = false, fsolved = false;
    int  fstep = 0;
    int  tstar = HWC - 1;

    // software-pipelined scan registers (prefetched for the NEXT step)
    float vn[16];
#pragma unroll
    for (int k = 0; k < 16; ++k) vn[k] = feT[(k << 6) + tid];

    int wpub = 0;   // next word (32 steps) to publish
    int wred = 0;   // first un-reduced word
    bool done = false;

    for (int phase = 0; phase < NPHASE && !done; ++phase) {
        const int wEnd = (3 + phase < NWORD) ? (3 + phase) : NWORD;

        while (wpub < wEnd) {
            unsigned word;
            if (!frozen) {
                word = 0u;
                const int tbeg = wpub * 32;
                for (int t = tbeg; t < tbeg + 32; ++t) {
                    // ---- local first-index argmax tree over prefetched values ----
                    float v[16];
#pragma unroll
                    for (int k = 0; k < 16; ++k) v[k] = vn[k];
                    const int cbase = tid * 16;
                    float v8[8]; int i8[8];
#pragma unroll
                    for (int k = 0; k < 8; ++k) {
                        bool tk = v[2 * k + 1] > v[2 * k];
                        v8[k] = tk ? v[2 * k + 1] : v[2 * k];
                        i8[k] = cbase + 2 * k + (tk ? 1 : 0);
                    }
                    float v4[4]; int i4a[4];
#pragma unroll
                    for (int k = 0; k < 4; ++k) {
                        bool tk = v8[2 * k + 1] > v8[2 * k];
                        v4[k] = tk ? v8[2 * k + 1] : v8[2 * k];
                        i4a[k] = tk ? i8[2 * k + 1] : i8[2 * k];
                    }
                    float v2[2]; int i2a[2];
#pragma unroll
                    for (int k = 0; k < 2; ++k) {
                        bool tk = v4[2 * k + 1] > v4[2 * k];
                        v2[k] = tk ? v4[2 * k + 1] : v4[2 * k];
                        i2a[k] = tk ? i4a[2 * k + 1] : i4a[2 * k];
                    }
                    bool tk0 = v2[1] > v2[0];
                    float bv = tk0 ? v2[1] : v2[0];
                    int   bi = tk0 ? i2a[1] : i2a[0];

                    // ---- global argmax: DPP value max; ballot picks lowest lane ----
                    float m = bv;
                    m = dppmax<0x111>(m);   // row_shr:1
                    m = dppmax<0x112>(m);   // row_shr:2
                    m = dppmax<0x114>(m);   // row_shr:4
                    m = dppmax<0x118>(m);   // row_shr:8
                    m = dppmax<0x142>(m);   // row_bcast:15
                    m = dppmax<0x143>(m);   // row_bcast:31
                    float gmax = __int_as_float(__builtin_amdgcn_readlane(__float_as_int(m), 63));
                    unsigned long long bl = __ballot(bv == gmax);
                    int lsel = (int)__ffsll(bl) - 1;
                    if (lsel < 0) lsel = 0;                 // insurance
                    const int  s      = __builtin_amdgcn_readlane(bi, lsel);
                    const bool solved = (s == goal);

                    // ---- unified update: ONE read group, then compute, then writes ----
                    bool changed = false;
                    float lidx = 0.0f;
                    if (tid < 9) {
                        const int  sy = s >> 5, sx = s & 31;
                        const int  cy = sy + dyj, cx = sx + dxj;
                        const bool ctr = (tid == 4);
                        const bool inb = ctr || (cy >= 0 && cy < GH && cx >= 0 && cx < GW);
                        const int  c  = (cy << 5) | cx;    // == s for center
                        const int  q  = inb ? c : s;
                        // single LDS round trip (reads precede ALL writes; neighbors never touch s)
                        const float gq = gg[q], oq = oo[q], hq = hi[q];
                        const float cmq = cmS[q], hhq = hhS[q];
                        const float gs = gg[s];
                        if (ctr) {
                            changed = (hq != 1.0f) || (!solved && oq != 0.0f);
                            hi[s] = 1.0f;
                            if (!solved) { oo[s] = 0.0f; feT[FEIDX(s)] = 0.0f; }
                        } else if (inb) {
                            const float kc = (dyj != 0 && dxj != 0) ? 1.4142f : 1.0f;
                            const float g2 = __fadd_rn(gs, kc);
                            const float t1 = __fmul_rn(__fsub_rn(1.0f, oq), __fsub_rn(1.0f, hq));
                            const float t2 = __fmul_rn(oq, (gq > g2) ? 1.0f : 0.0f);
                            const float idxv = __fmul_rn(__fadd_rn(t1, t2), cmq);
                            lidx = idxv;
                            if (idxv != 0.0f) {
                                changed = true;
                                const float omi = __fsub_rn(1.0f, idxv);
                                const float gn = __fadd_rn(__fmul_rn(g2, idxv), __fmul_rn(gq, omi));
                                const float on = fminf(__fadd_rn(oq, idxv), 1.0f);
                                gg[c] = gn; oo[c] = on;
                                feT[FEIDX(c)] = fe_expr(gn, hhq, on);
                            }
                        }
                        slog[t * 9 + tid] = ctr ? (unsigned)s : __float_as_uint(lidx);
                    }

                    // ---- prefetch next step's scan (overlaps bookkeeping + latch) ----
#pragma unroll
                    for (int k = 0; k < 16; ++k) vn[k] = feT[(k << 6) + tid];

                    unsigned long long chg = __ballot(changed);
                    if (solved) word |= (1u << (t & 31));
                    if (chg == 0ull) {   // fixed point: identical selection forever
                        if (solved) word |= ~((1u << (t & 31)) - 1u);
                        frozen = true; fsolved = solved; fstep = t;
                        break;
                    }
                }
            } else {
                word = fsolved ? 0xFFFFFFFFu : 0u;
            }
            if (tid == 0)
                __hip_atomic_store(&swin[wpub * NB + b], word, __ATOMIC_RELEASE, __HIP_MEMORY_SCOPE_AGENT);
            ++wpub;
        }

        // ---- publish status, device barrier ----
        if (tid == 0) {
            __hip_atomic_store(&stw[phase * NB + b], frozen ? (fsolved ? 1u : 2u) : 0u,
                               __ATOMIC_RELEASE, __HIP_MEMORY_SCOPE_AGENT);
            __hip_atomic_fetch_add(&bar[phase], 1u, __ATOMIC_ACQ_REL, __HIP_MEMORY_SCOPE_AGENT);
        }
        {
            unsigned guard = 0u;
            while (__hip_atomic_load(&bar[phase], __ATOMIC_ACQUIRE, __HIP_MEMORY_SCOPE_AGENT) < NB) {
                __builtin_amdgcn_s_sleep(1);
                if (++guard > 16000000u) break;   // watchdog (never hit in practice)
            }
        }

        // ---- redundant reduce of words [wred, wEnd): all blocks same decision ----
        for (int w = wred; w < wEnd; ++w) {
            unsigned wv = __hip_atomic_load(&swin[w * NB + (tid & 31)], __ATOMIC_ACQUIRE, __HIP_MEMORY_SCOPE_AGENT);
            unsigned A = wv;
            A = dppand<0x111>(A); A = dppand<0x112>(A); A = dppand<0x114>(A);
            A = dppand<0x118>(A); A = dppand<0x142>(A); A = dppand<0x143>(A);
            A = (unsigned)__builtin_amdgcn_readlane((int)A, 63);
            if (A) { tstar = w * 32 + (__ffs(A) - 1); done = true; break; }
        }
        wred = wEnd;
        if (!done) {
            unsigned sv = __hip_atomic_load(&stw[phase * NB + (tid & 31)], __ATOMIC_ACQUIRE, __HIP_MEMORY_SCOPE_AGENT);
            if (__ballot(sv != 0u) == 0xFFFFFFFFFFFFFFFFull) done = true;  // all frozen: tstar stays 1023
        }
    }
    __syncthreads();

    // ================= epilogue (per block, all from LDS) =================
    const int Tl = frozen ? min(tstar, fstep) : tstar;

    // hist = union of selected cells for t <= Tl (rebuild; live hi may overshoot tstar)
#pragma unroll
    for (int q = 0; q < 4; ++q)
        ((float4*)hi)[tid + (q << 6)] = make_float4(0.f, 0.f, 0.f, 0.f);
    __syncthreads();
    for (int t = tid; t <= Tl; t += 64) hi[(int)slog[t * 9 + 4]] = 1.0f;
    __syncthreads();
#pragma unroll
    for (int q = 0; q < 4; ++q) {
        int i4 = tid + (q << 6);
        ((float4*)(out + b * HWC))[i4] = ((const float4*)hi)[i4];
    }

    // parents replay into cmS (reused as pp); path buffer = hhS (reused as pb)
    const float goalf = (float)goal;
#pragma unroll
    for (int k = 0; k < 16; ++k) {
        int i = tid * 16 + k;
        cmS[i] = goalf;    // pp
        hhS[i] = 0.0f;     // pb
    }
    __syncthreads();
    if (tid < 9 && tid != 4) {
        for (int t0c = 0; t0c <= Tl; t0c += 16) {
            // chunked slog preload: one parallel read group per 16 steps
            float iv[16], sv[16];
#pragma unroll
            for (int u = 0; u < 16; ++u) {
                int t = t0c + u;
                if (t <= Tl) {
                    iv[u] = __uint_as_float(slog[t * 9 + tid]);
                    sv[u] = (float)(int)slog[t * 9 + 4];
                } else {
                    iv[u] = 0.0f; sv[u] = 0.0f;
                }
            }
#pragma unroll
            for (int u = 0; u < 16; ++u) {
                if (iv[u] != 0.0f) {
                    int c = (int)sv[u] + (dyj << 5) + dxj;   // idxv!=0 implies in-bounds
                    float omi = __fsub_rn(1.0f, iv[u]);
                    cmS[c] = __fadd_rn(__fmul_rn(sv[u], iv[u]), __fmul_rn(cmS[c], omi));
                }
            }
        }
    }
    __syncthreads();

    // backtrack: tstar iterations, JAX index semantics, revisit break
    if (tid == 0) {
        hhS[goal] = 1.0f;
        int loc = (int)cmS[goal];
        for (int i2 = 0; i2 < tstar; ++i2) {
            int w = (loc < 0) ? loc + HWC : loc;              // JAX wraps negatives once
            if (w >= 0 && w < HWC) {
                if (hhS[w] == 1.0f) break;                    // revisit: chase cycles, no new cells
                hhS[w] = 1.0f;
            }
            int gidx = w < 0 ? 0 : (w > HWC - 1 ? HWC - 1 : w);
            loc = (int)cmS[gidx];
        }
    }
    __syncthreads();
#pragma unroll
    for (int q = 0; q < 4; ++q) {
        int i4 = tid + (q << 6);
        ((float4*)(out + NB * HWC + b * HWC))[i4] = ((const float4*)hhS)[i4];
    }
}

extern "C" void kernel_launch(void* const* d_in, const int* in_sizes, int n_in,
                              void* d_out, int out_size, void* d_ws, size_t ws_size,
                              hipStream_t stream)
{
    const float* cm = (const float*)d_in[0];
    const float* sm = (const float*)d_in[1];
    const float* gm = (const float*)d_in[2];
    float* out = (float*)d_out;

    unsigned* bar  = (unsigned*)((char*)d_ws + WS_BAR);
    unsigned* swin = (unsigned*)((char*)d_ws + WS_SWIN);
    unsigned* stw  = (unsigned*)((char*)d_ws + WS_STW);

    dastar_init<<<1, 64, 0, stream>>>(bar);
    dastar_fused<<<dim3(NB), dim3(64), 0, stream>>>(cm, sm, gm, swin, stw, bar, out);
}